// Round 1
// baseline (2123.119 us; speedup 1.0000x reference)
//
#include <hip/hip_runtime.h>

#define NNODES 50000
#define NEDGES 800000

__global__ void deg_kernel(const int* __restrict__ dst, float* __restrict__ degf, int nE) {
    int i = blockIdx.x * blockDim.x + threadIdx.x;
    if (i < nE) atomicAdd(&degf[dst[i]], 1.0f);
}

__global__ void dinv_kernel(const float* __restrict__ degf, float* __restrict__ dinv, int n) {
    int i = blockIdx.x * blockDim.x + threadIdx.x;
    if (i < n) dinv[i] = 1.0f / sqrtf(degf[i] + 1.0f);
}

// C = X[N,128] @ W[128,NOUT]; H = C raw; A = dinv[r]^2 * C + bias  (self-loop + bias fused)
template<int NOUT, bool RELU_IN>
__global__ __launch_bounds__(256) void gemm_kernel(
    const float* __restrict__ X, const float* __restrict__ W,
    const float* __restrict__ bias, const float* __restrict__ dinv,
    float* __restrict__ H, float* __restrict__ A, int N)
{
    constexpr int K = 128, BR = 64, KC = 32, JT = NOUT / 8; // JT cols per thread
    __shared__ float Ws[KC * NOUT];
    __shared__ float Xs[BR][36];              // pad 36: conflict-free, 16B-aligned rows
    const int tid = threadIdx.x;
    const int cg = tid & 7;                   // col group 0..7
    const int rg = tid >> 3;                  // row group 0..31 (2 rows each)
    const int row0 = blockIdx.x * BR;

    float acc0[JT], acc1[JT];
#pragma unroll
    for (int j = 0; j < JT; ++j) { acc0[j] = 0.f; acc1[j] = 0.f; }

    for (int kc = 0; kc < K; kc += KC) {
        __syncthreads();
        {   // W chunk: contiguous KC*NOUT floats starting at W + kc*NOUT
            constexpr int TOT4 = KC * NOUT / 4;
            const float4* Wg = (const float4*)(W + kc * NOUT);
            float4* Wl = (float4*)Ws;
            for (int i = tid; i < TOT4; i += 256) Wl[i] = Wg[i];
        }
        {   // X chunk: 64 rows x 32 cols = 512 float4
            for (int i = tid; i < BR * 8; i += 256) {
                int r = i >> 3, c4 = i & 7;
                int gr = row0 + r;
                float4 v = make_float4(0.f, 0.f, 0.f, 0.f);
                if (gr < N) v = *(const float4*)(X + (size_t)gr * K + kc + c4 * 4);
                if (RELU_IN) {
                    v.x = fmaxf(v.x, 0.f); v.y = fmaxf(v.y, 0.f);
                    v.z = fmaxf(v.z, 0.f); v.w = fmaxf(v.w, 0.f);
                }
                *(float4*)&Xs[r][c4 * 4] = v;
            }
        }
        __syncthreads();
#pragma unroll
        for (int k = 0; k < KC; ++k) {
            float x0 = Xs[rg * 2 + 0][k];
            float x1 = Xs[rg * 2 + 1][k];
#pragma unroll
            for (int j4 = 0; j4 < JT / 4; ++j4) {
                float4 w = *(const float4*)&Ws[k * NOUT + cg * JT + j4 * 4];
                acc0[j4*4+0] += x0 * w.x; acc0[j4*4+1] += x0 * w.y;
                acc0[j4*4+2] += x0 * w.z; acc0[j4*4+3] += x0 * w.w;
                acc1[j4*4+0] += x1 * w.x; acc1[j4*4+1] += x1 * w.y;
                acc1[j4*4+2] += x1 * w.z; acc1[j4*4+3] += x1 * w.w;
            }
        }
    }

    // epilogue: write H (raw) and A = dinv^2*H + bias
#pragma unroll
    for (int rr = 0; rr < 2; ++rr) {
        int r = row0 + rg * 2 + rr;
        if (r >= N) continue;
        float dv = dinv[r];
        float scale = dv * dv;
        const float* ac = rr ? acc1 : acc0;
#pragma unroll
        for (int j4 = 0; j4 < JT / 4; ++j4) {
            int col = cg * JT + j4 * 4;
            float4 h, a;
            h.x = ac[j4*4+0]; h.y = ac[j4*4+1]; h.z = ac[j4*4+2]; h.w = ac[j4*4+3];
            float4 bv = *(const float4*)(bias + col);
            a.x = h.x * scale + bv.x; a.y = h.y * scale + bv.y;
            a.z = h.z * scale + bv.z; a.w = h.w * scale + bv.w;
            *(float4*)(H + (size_t)r * NOUT + col) = h;
            *(float4*)(A + (size_t)r * NOUT + col) = a;
        }
    }
}

// A[dst] += dinv[src]*dinv[dst] * H[src]   (NOUT/4 threads per edge, float4 each)
template<int NOUT>
__global__ __launch_bounds__(256) void scatter_kernel(
    const int* __restrict__ src, const int* __restrict__ dst,
    const float* __restrict__ dinv, const float* __restrict__ H,
    float* __restrict__ A, int nE)
{
    constexpr int TPE = NOUT / 4;
    int idx = blockIdx.x * 256 + threadIdx.x;
    int e = idx / TPE, l = idx % TPE;
    if (e >= nE) return;
    int s = src[e], d = dst[e];
    float norm = dinv[s] * dinv[d];
    float4 v = *(const float4*)(H + (size_t)s * NOUT + l * 4);
    float* base = A + (size_t)d * NOUT + l * 4;
    atomicAdd(base + 0, v.x * norm);
    atomicAdd(base + 1, v.y * norm);
    atomicAdd(base + 2, v.z * norm);
    atomicAdd(base + 3, v.w * norm);
}

extern "C" void kernel_launch(void* const* d_in, const int* in_sizes, int n_in,
                              void* d_out, int out_size, void* d_ws, size_t ws_size,
                              hipStream_t stream) {
    const float* x  = (const float*)d_in[0];
    const int*   ei = (const int*)d_in[1];
    const float* W1 = (const float*)d_in[2];
    const float* b1 = (const float*)d_in[3];
    const float* W2 = (const float*)d_in[4];
    const float* b2 = (const float*)d_in[5];
    float* out = (float*)d_out;
    float* ws  = (float*)d_ws;

    const int* srcA = ei;
    const int* dstA = ei + NEDGES;

    float* degf = ws;                       // 50000
    float* dinv = ws + 50000;               // 50000
    float* h1   = ws + 100000;              // 50000*128
    float* a1   = h1 + (size_t)NNODES*128;  // 50000*128
    float* h2   = a1 + (size_t)NNODES*128;  // 50000*64

    hipMemsetAsync(degf, 0, NNODES * sizeof(float), stream);
    deg_kernel<<<(NEDGES + 255) / 256, 256, 0, stream>>>(dstA, degf, NEDGES);
    dinv_kernel<<<(NNODES + 255) / 256, 256, 0, stream>>>(degf, dinv, NNODES);

    // layer 1: h1 = x@W1 ; a1 = dinv^2*h1 + b1 ; a1[dst] += norm*h1[src]
    gemm_kernel<128, false><<<(NNODES + 63) / 64, 256, 0, stream>>>(x, W1, b1, dinv, h1, a1, NNODES);
    scatter_kernel<128><<<(NEDGES * 32 + 255) / 256, 256, 0, stream>>>(srcA, dstA, dinv, h1, a1, NEDGES);

    // layer 2: x2 = relu(a1); h2 = x2@W2 ; out = dinv^2*h2 + b2 ; out[dst] += norm*h2[src]
    gemm_kernel<64, true><<<(NNODES + 63) / 64, 256, 0, stream>>>(a1, W2, b2, dinv, h2, out, NNODES);
    scatter_kernel<64><<<(NEDGES * 16 + 255) / 256, 256, 0, stream>>>(srcA, dstA, dinv, h2, out, NEDGES);
}

// Round 2
// 357.726 us; speedup vs baseline: 5.9350x; 5.9350x over previous
//
#include <hip/hip_runtime.h>

#define NNODES 50000
#define NEDGES 800000

__global__ void deg_kernel(const int* __restrict__ dst, int* __restrict__ deg, int nE) {
    int i = blockIdx.x * blockDim.x + threadIdx.x;
    if (i < nE) atomicAdd(&deg[dst[i]], 1);
}

__global__ void dinv_kernel(const int* __restrict__ deg, float* __restrict__ dinv, int n) {
    int i = blockIdx.x * blockDim.x + threadIdx.x;
    if (i < n) dinv[i] = 1.0f / sqrtf((float)deg[i] + 1.0f);
}

// single-block exclusive prefix scan over deg[0..n) -> offs, cursor
__global__ __launch_bounds__(1024) void scan_kernel(const int* __restrict__ deg,
        int* __restrict__ offs, int* __restrict__ cursor, int n) {
    __shared__ int sm[1024];
    __shared__ int carry_s;
    int tid = threadIdx.x;
    if (tid == 0) carry_s = 0;
    __syncthreads();
    for (int base = 0; base < n; base += 1024) {
        int i = base + tid;
        int v = (i < n) ? deg[i] : 0;
        sm[tid] = v;
        __syncthreads();
        for (int off = 1; off < 1024; off <<= 1) {
            int t = (tid >= off) ? sm[tid - off] : 0;
            __syncthreads();
            sm[tid] += t;
            __syncthreads();
        }
        int carry = carry_s;
        int exc = sm[tid] - v + carry;
        if (i < n) { offs[i] = exc; cursor[i] = exc; }
        __syncthreads();
        if (tid == 0) carry_s = carry + sm[1023];
        __syncthreads();
    }
    if (tid == 0) offs[n] = carry_s;
}

// bucket edges by dst: csr[pos] = src   (cursor[d] ends at end-offset)
__global__ void fill_kernel(const int* __restrict__ src, const int* __restrict__ dst,
        int* __restrict__ cursor, int* __restrict__ csr, int nE) {
    int e = blockIdx.x * blockDim.x + threadIdx.x;
    if (e < nE) {
        int d = dst[e];
        int pos = atomicAdd(&cursor[d], 1);
        csr[pos] = src[e];
    }
}

// H = X[N,128] @ W[128,NOUT]  (optionally relu on input load)
template<int NOUT, bool RELU_IN>
__global__ __launch_bounds__(256) void gemm_kernel(
    const float* __restrict__ X, const float* __restrict__ W,
    float* __restrict__ H, int N)
{
    constexpr int K = 128, BR = 64, KC = 32, JT = NOUT / 8;
    __shared__ float Ws[KC * NOUT];
    __shared__ float Xs[BR][36];
    const int tid = threadIdx.x;
    const int cg = tid & 7;
    const int rg = tid >> 3;
    const int row0 = blockIdx.x * BR;

    float acc0[JT], acc1[JT];
#pragma unroll
    for (int j = 0; j < JT; ++j) { acc0[j] = 0.f; acc1[j] = 0.f; }

    for (int kc = 0; kc < K; kc += KC) {
        __syncthreads();
        {
            constexpr int TOT4 = KC * NOUT / 4;
            const float4* Wg = (const float4*)(W + kc * NOUT);
            float4* Wl = (float4*)Ws;
            for (int i = tid; i < TOT4; i += 256) Wl[i] = Wg[i];
        }
        {
            for (int i = tid; i < BR * 8; i += 256) {
                int r = i >> 3, c4 = i & 7;
                int gr = row0 + r;
                float4 v = make_float4(0.f, 0.f, 0.f, 0.f);
                if (gr < N) v = *(const float4*)(X + (size_t)gr * K + kc + c4 * 4);
                if (RELU_IN) {
                    v.x = fmaxf(v.x, 0.f); v.y = fmaxf(v.y, 0.f);
                    v.z = fmaxf(v.z, 0.f); v.w = fmaxf(v.w, 0.f);
                }
                *(float4*)&Xs[r][c4 * 4] = v;
            }
        }
        __syncthreads();
#pragma unroll
        for (int k = 0; k < KC; ++k) {
            float x0 = Xs[rg * 2 + 0][k];
            float x1 = Xs[rg * 2 + 1][k];
#pragma unroll
            for (int j4 = 0; j4 < JT / 4; ++j4) {
                float4 w = *(const float4*)&Ws[k * NOUT + cg * JT + j4 * 4];
                acc0[j4*4+0] += x0 * w.x; acc0[j4*4+1] += x0 * w.y;
                acc0[j4*4+2] += x0 * w.z; acc0[j4*4+3] += x0 * w.w;
                acc1[j4*4+0] += x1 * w.x; acc1[j4*4+1] += x1 * w.y;
                acc1[j4*4+2] += x1 * w.z; acc1[j4*4+3] += x1 * w.w;
            }
        }
    }

#pragma unroll
    for (int rr = 0; rr < 2; ++rr) {
        int r = row0 + rg * 2 + rr;
        if (r >= N) continue;
        const float* ac = rr ? acc1 : acc0;
#pragma unroll
        for (int j4 = 0; j4 < JT / 4; ++j4) {
            int col = cg * JT + j4 * 4;
            float4 h;
            h.x = ac[j4*4+0]; h.y = ac[j4*4+1]; h.z = ac[j4*4+2]; h.w = ac[j4*4+3];
            *(float4*)(H + (size_t)r * NOUT + col) = h;
        }
    }
}

// Out[n] = bias + dinv[n] * ( dinv[n]*H[n] + sum_{s in csr[n]} dinv[s]*H[s] )
template<int NOUT>
__global__ __launch_bounds__(256) void agg_kernel(
        const int* __restrict__ offs, const int* __restrict__ endo,
        const int* __restrict__ csr, const float* __restrict__ dinv,
        const float* __restrict__ H, const float* __restrict__ bias,
        float* __restrict__ Out, int nNodes)
{
    constexpr int TPN = NOUT / 4;       // threads per node (float4 each)
    constexpr int NPB = 256 / TPN;      // nodes per block
    int g = threadIdx.x / TPN;
    int l = threadIdx.x % TPN;
    int n = blockIdx.x * NPB + g;
    if (n >= nNodes) return;
    float dn = dinv[n];
    const size_t loff = (size_t)l * 4;
    float4 self = *(const float4*)(H + (size_t)n * NOUT + loff);
    float4 acc;
    acc.x = dn * self.x; acc.y = dn * self.y; acc.z = dn * self.z; acc.w = dn * self.w;
    int i = offs[n], e0 = endo[n];
    for (; i + 4 <= e0; i += 4) {
        int sa = csr[i], sb = csr[i+1], sc = csr[i+2], sd = csr[i+3];
        float da = dinv[sa], db = dinv[sb], dc = dinv[sc], dd = dinv[sd];
        float4 va = *(const float4*)(H + (size_t)sa * NOUT + loff);
        float4 vb = *(const float4*)(H + (size_t)sb * NOUT + loff);
        float4 vc = *(const float4*)(H + (size_t)sc * NOUT + loff);
        float4 vd = *(const float4*)(H + (size_t)sd * NOUT + loff);
        acc.x += da*va.x + db*vb.x + dc*vc.x + dd*vd.x;
        acc.y += da*va.y + db*vb.y + dc*vc.y + dd*vd.y;
        acc.z += da*va.z + db*vb.z + dc*vc.z + dd*vd.z;
        acc.w += da*va.w + db*vb.w + dc*vc.w + dd*vd.w;
    }
    for (; i < e0; ++i) {
        int s = csr[i];
        float ds = dinv[s];
        float4 v = *(const float4*)(H + (size_t)s * NOUT + loff);
        acc.x += ds*v.x; acc.y += ds*v.y; acc.z += ds*v.z; acc.w += ds*v.w;
    }
    float4 bv = *(const float4*)(bias + loff);
    float4 o;
    o.x = bv.x + dn*acc.x; o.y = bv.y + dn*acc.y;
    o.z = bv.z + dn*acc.z; o.w = bv.w + dn*acc.w;
    *(float4*)(Out + (size_t)n * NOUT + loff) = o;
}

extern "C" void kernel_launch(void* const* d_in, const int* in_sizes, int n_in,
                              void* d_out, int out_size, void* d_ws, size_t ws_size,
                              hipStream_t stream) {
    const float* x  = (const float*)d_in[0];
    const int*   ei = (const int*)d_in[1];
    const float* W1 = (const float*)d_in[2];
    const float* b1 = (const float*)d_in[3];
    const float* W2 = (const float*)d_in[4];
    const float* b2 = (const float*)d_in[5];
    float* out = (float*)d_out;
    char* wsb  = (char*)d_ws;

    const int* srcA = ei;
    const int* dstA = ei + NEDGES;

    int*   deg    = (int*)wsb;                          // 50000
    int*   offs   = deg + NNODES;                       // 50001
    int*   cursor = offs + NNODES + 1;                  // 50000
    float* dinv   = (float*)(cursor + NNODES);          // 50000
    int*   csr    = (int*)(dinv + NNODES);              // 800000
    float* h1     = (float*)(csr + NEDGES + 3);         // 50000*128 (16B-align ok: offset mult of 4)
    float* a1     = h1 + (size_t)NNODES * 128;          // 50000*128
    float* h2     = a1 + (size_t)NNODES * 128;          // 50000*64

    hipMemsetAsync(deg, 0, NNODES * sizeof(int), stream);
    deg_kernel<<<(NEDGES + 255) / 256, 256, 0, stream>>>(dstA, deg, NEDGES);
    dinv_kernel<<<(NNODES + 255) / 256, 256, 0, stream>>>(deg, dinv, NNODES);
    scan_kernel<<<1, 1024, 0, stream>>>(deg, offs, cursor, NNODES);
    fill_kernel<<<(NEDGES + 255) / 256, 256, 0, stream>>>(srcA, dstA, cursor, csr, NEDGES);

    // layer 1
    gemm_kernel<128, false><<<(NNODES + 63) / 64, 256, 0, stream>>>(x, W1, h1, NNODES);
    agg_kernel<128><<<(NNODES * 32 + 255) / 256, 256, 0, stream>>>(offs, cursor, csr, dinv, h1, b1, a1, NNODES);

    // layer 2 (relu fused into gemm input load)
    gemm_kernel<64, true><<<(NNODES + 63) / 64, 256, 0, stream>>>(a1, W2, h2, NNODES);
    agg_kernel<64><<<(NNODES * 16 + 255) / 256, 256, 0, stream>>>(offs, cursor, csr, dinv, h2, b2, out, NNODES);
}

// Round 3
// 275.546 us; speedup vs baseline: 7.7051x; 1.2982x over previous
//
#include <hip/hip_runtime.h>

#define NNODES 50000
#define NEDGES 800000
#define NSCB ((NNODES + 255) / 256)   // 196 scan blocks

__global__ void deg_kernel(const int* __restrict__ dst, int* __restrict__ deg, int nE) {
    int i = blockIdx.x * blockDim.x + threadIdx.x;
    if (i < nE) atomicAdd(&deg[dst[i]], 1);
}

__global__ void dinv_kernel(const int* __restrict__ deg, float* __restrict__ dinv, int n) {
    int i = blockIdx.x * blockDim.x + threadIdx.x;
    if (i < n) dinv[i] = 1.0f / sqrtf((float)deg[i] + 1.0f);
}

// ---- hierarchical exclusive scan: local -> block-sums -> add ----
__global__ __launch_bounds__(256) void scan_local(const int* __restrict__ deg,
        int* __restrict__ exc, int* __restrict__ bsum, int n) {
    __shared__ int sm[256];
    int tid = threadIdx.x;
    int i = blockIdx.x * 256 + tid;
    int v = (i < n) ? deg[i] : 0;
    sm[tid] = v;
    __syncthreads();
    for (int off = 1; off < 256; off <<= 1) {
        int t = (tid >= off) ? sm[tid - off] : 0;
        __syncthreads();
        sm[tid] += t;
        __syncthreads();
    }
    if (i < n) exc[i] = sm[tid] - v;          // exclusive within block
    if (tid == 255) bsum[blockIdx.x] = sm[255];
}

__global__ __launch_bounds__(256) void scan_bsum(int* __restrict__ bsum, int nb) {
    __shared__ int sm[256];
    int tid = threadIdx.x;
    int v = (tid < nb) ? bsum[tid] : 0;
    sm[tid] = v;
    __syncthreads();
    for (int off = 1; off < 256; off <<= 1) {
        int t = (tid >= off) ? sm[tid - off] : 0;
        __syncthreads();
        sm[tid] += t;
        __syncthreads();
    }
    if (tid < nb) bsum[tid] = sm[tid] - v;    // exclusive block offsets
}

__global__ void scan_add(int* __restrict__ offs, int* __restrict__ cursor,
        const int* __restrict__ bsum, int n) {
    int i = blockIdx.x * 256 + threadIdx.x;
    if (i < n) {
        int o = offs[i] + bsum[blockIdx.x];
        offs[i] = o;
        cursor[i] = o;
    }
}

// bucket edges by dst: csr[pos] = src   (cursor[d] ends at end-offset)
__global__ void fill_kernel(const int* __restrict__ src, const int* __restrict__ dst,
        int* __restrict__ cursor, int* __restrict__ csr, int nE) {
    int e = blockIdx.x * blockDim.x + threadIdx.x;
    if (e < nE) {
        int d = dst[e];
        int pos = atomicAdd(&cursor[d], 1);
        csr[pos] = src[e];
    }
}

// H = X[N,128] @ W[128,NOUT]  (optionally relu on input load)
template<int NOUT, bool RELU_IN>
__global__ __launch_bounds__(256) void gemm_kernel(
    const float* __restrict__ X, const float* __restrict__ W,
    float* __restrict__ H, int N)
{
    constexpr int K = 128, BR = 64, KC = 32, JT = NOUT / 8;
    __shared__ float Ws[KC * NOUT];
    __shared__ float Xs[BR][36];
    const int tid = threadIdx.x;
    const int cg = tid & 7;
    const int rg = tid >> 3;
    const int row0 = blockIdx.x * BR;

    float acc0[JT], acc1[JT];
#pragma unroll
    for (int j = 0; j < JT; ++j) { acc0[j] = 0.f; acc1[j] = 0.f; }

    for (int kc = 0; kc < K; kc += KC) {
        __syncthreads();
        {
            constexpr int TOT4 = KC * NOUT / 4;
            const float4* Wg = (const float4*)(W + kc * NOUT);
            float4* Wl = (float4*)Ws;
            for (int i = tid; i < TOT4; i += 256) Wl[i] = Wg[i];
        }
        {
            for (int i = tid; i < BR * 8; i += 256) {
                int r = i >> 3, c4 = i & 7;
                int gr = row0 + r;
                float4 v = make_float4(0.f, 0.f, 0.f, 0.f);
                if (gr < N) v = *(const float4*)(X + (size_t)gr * K + kc + c4 * 4);
                if (RELU_IN) {
                    v.x = fmaxf(v.x, 0.f); v.y = fmaxf(v.y, 0.f);
                    v.z = fmaxf(v.z, 0.f); v.w = fmaxf(v.w, 0.f);
                }
                *(float4*)&Xs[r][c4 * 4] = v;
            }
        }
        __syncthreads();
#pragma unroll
        for (int k = 0; k < KC; ++k) {
            float x0 = Xs[rg * 2 + 0][k];
            float x1 = Xs[rg * 2 + 1][k];
#pragma unroll
            for (int j4 = 0; j4 < JT / 4; ++j4) {
                float4 w = *(const float4*)&Ws[k * NOUT + cg * JT + j4 * 4];
                acc0[j4*4+0] += x0 * w.x; acc0[j4*4+1] += x0 * w.y;
                acc0[j4*4+2] += x0 * w.z; acc0[j4*4+3] += x0 * w.w;
                acc1[j4*4+0] += x1 * w.x; acc1[j4*4+1] += x1 * w.y;
                acc1[j4*4+2] += x1 * w.z; acc1[j4*4+3] += x1 * w.w;
            }
        }
    }

#pragma unroll
    for (int rr = 0; rr < 2; ++rr) {
        int r = row0 + rg * 2 + rr;
        if (r >= N) continue;
        const float* ac = rr ? acc1 : acc0;
#pragma unroll
        for (int j4 = 0; j4 < JT / 4; ++j4) {
            int col = cg * JT + j4 * 4;
            float4 h;
            h.x = ac[j4*4+0]; h.y = ac[j4*4+1]; h.z = ac[j4*4+2]; h.w = ac[j4*4+3];
            *(float4*)(H + (size_t)r * NOUT + col) = h;
        }
    }
}

// Out[n] = bias + dinv[n] * ( dinv[n]*H[n] + sum_{s in csr[n]} dinv[s]*H[s] )
template<int NOUT>
__global__ __launch_bounds__(256) void agg_kernel(
        const int* __restrict__ offs, const int* __restrict__ endo,
        const int* __restrict__ csr, const float* __restrict__ dinv,
        const float* __restrict__ H, const float* __restrict__ bias,
        float* __restrict__ Out, int nNodes)
{
    constexpr int TPN = NOUT / 4;       // threads per node (float4 each)
    constexpr int NPB = 256 / TPN;      // nodes per block
    int g = threadIdx.x / TPN;
    int l = threadIdx.x % TPN;
    int n = blockIdx.x * NPB + g;
    if (n >= nNodes) return;
    float dn = dinv[n];
    const size_t loff = (size_t)l * 4;
    float4 self = *(const float4*)(H + (size_t)n * NOUT + loff);
    float4 acc;
    acc.x = dn * self.x; acc.y = dn * self.y; acc.z = dn * self.z; acc.w = dn * self.w;
    int i = offs[n], e0 = endo[n];
    for (; i + 4 <= e0; i += 4) {
        int sa = csr[i], sb = csr[i+1], sc = csr[i+2], sd = csr[i+3];
        float da = dinv[sa], db = dinv[sb], dc = dinv[sc], dd = dinv[sd];
        float4 va = *(const float4*)(H + (size_t)sa * NOUT + loff);
        float4 vb = *(const float4*)(H + (size_t)sb * NOUT + loff);
        float4 vc = *(const float4*)(H + (size_t)sc * NOUT + loff);
        float4 vd = *(const float4*)(H + (size_t)sd * NOUT + loff);
        acc.x += da*va.x + db*vb.x + dc*vc.x + dd*vd.x;
        acc.y += da*va.y + db*vb.y + dc*vc.y + dd*vd.y;
        acc.z += da*va.z + db*vb.z + dc*vc.z + dd*vd.z;
        acc.w += da*va.w + db*vb.w + dc*vc.w + dd*vd.w;
    }
    for (; i < e0; ++i) {
        int s = csr[i];
        float ds = dinv[s];
        float4 v = *(const float4*)(H + (size_t)s * NOUT + loff);
        acc.x += ds*v.x; acc.y += ds*v.y; acc.z += ds*v.z; acc.w += ds*v.w;
    }
    float4 bv = *(const float4*)(bias + loff);
    float4 o;
    o.x = bv.x + dn*acc.x; o.y = bv.y + dn*acc.y;
    o.z = bv.z + dn*acc.z; o.w = bv.w + dn*acc.w;
    *(float4*)(Out + (size_t)n * NOUT + loff) = o;
}

extern "C" void kernel_launch(void* const* d_in, const int* in_sizes, int n_in,
                              void* d_out, int out_size, void* d_ws, size_t ws_size,
                              hipStream_t stream) {
    const float* x  = (const float*)d_in[0];
    const int*   ei = (const int*)d_in[1];
    const float* W1 = (const float*)d_in[2];
    const float* b1 = (const float*)d_in[3];
    const float* W2 = (const float*)d_in[4];
    const float* b2 = (const float*)d_in[5];
    float* out = (float*)d_out;
    char* wsb  = (char*)d_ws;

    const int* srcA = ei;
    const int* dstA = ei + NEDGES;

    int*   deg    = (int*)wsb;                          // 50000
    int*   offs   = deg + NNODES;                       // 50001
    int*   cursor = offs + NNODES + 1;                  // 50000
    float* dinv   = (float*)(cursor + NNODES);          // 50000
    int*   bsum   = (int*)(dinv + NNODES);              // 256
    int*   csr    = bsum + 256;                         // 800000
    float* h1     = (float*)(csr + NEDGES + 3);         // 50000*128
    float* a1     = h1 + (size_t)NNODES * 128;          // 50000*128
    float* h2     = a1 + (size_t)NNODES * 128;          // 50000*64

    hipMemsetAsync(deg, 0, NNODES * sizeof(int), stream);
    deg_kernel<<<(NEDGES + 255) / 256, 256, 0, stream>>>(dstA, deg, NEDGES);
    dinv_kernel<<<(NNODES + 255) / 256, 256, 0, stream>>>(deg, dinv, NNODES);
    scan_local<<<NSCB, 256, 0, stream>>>(deg, offs, bsum, NNODES);
    scan_bsum<<<1, 256, 0, stream>>>(bsum, NSCB);
    scan_add<<<NSCB, 256, 0, stream>>>(offs, cursor, bsum, NNODES);
    fill_kernel<<<(NEDGES + 255) / 256, 256, 0, stream>>>(srcA, dstA, cursor, csr, NEDGES);

    // layer 1
    gemm_kernel<128, false><<<(NNODES + 63) / 64, 256, 0, stream>>>(x, W1, h1, NNODES);
    agg_kernel<128><<<(NNODES * 32 + 255) / 256, 256, 0, stream>>>(offs, cursor, csr, dinv, h1, b1, a1, NNODES);

    // layer 2 (relu fused into gemm input load)
    gemm_kernel<64, true><<<(NNODES + 63) / 64, 256, 0, stream>>>(a1, W2, h2, NNODES);
    agg_kernel<64><<<(NNODES * 16 + 255) / 256, 256, 0, stream>>>(offs, cursor, csr, dinv, h2, b2, out, NNODES);
}

// Round 4
// 270.543 us; speedup vs baseline: 7.8476x; 1.0185x over previous
//
#include <hip/hip_runtime.h>

#define NNODES 50000
#define NEDGES 800000
#define NSCB ((NNODES + 255) / 256)   // 196 scan blocks

__global__ void deg_kernel(const int* __restrict__ dst, int* __restrict__ deg, int nE) {
    int i = blockIdx.x * blockDim.x + threadIdx.x;
    if (i < nE) atomicAdd(&deg[dst[i]], 1);
}

// ---- hierarchical exclusive scan: local (+dinv) -> block-sums -> add ----
__global__ __launch_bounds__(256) void scan_local(const int* __restrict__ deg,
        int* __restrict__ exc, int* __restrict__ bsum, float* __restrict__ dinv, int n) {
    __shared__ int sm[256];
    int tid = threadIdx.x;
    int i = blockIdx.x * 256 + tid;
    int v = (i < n) ? deg[i] : 0;
    sm[tid] = v;
    __syncthreads();
    for (int off = 1; off < 256; off <<= 1) {
        int t = (tid >= off) ? sm[tid - off] : 0;
        __syncthreads();
        sm[tid] += t;
        __syncthreads();
    }
    if (i < n) {
        exc[i] = sm[tid] - v;                    // exclusive within block
        dinv[i] = 1.0f / sqrtf((float)v + 1.0f); // fused dinv
    }
    if (tid == 255) bsum[blockIdx.x] = sm[255];
}

__global__ __launch_bounds__(256) void scan_bsum(int* __restrict__ bsum, int nb) {
    __shared__ int sm[256];
    int tid = threadIdx.x;
    int v = (tid < nb) ? bsum[tid] : 0;
    sm[tid] = v;
    __syncthreads();
    for (int off = 1; off < 256; off <<= 1) {
        int t = (tid >= off) ? sm[tid - off] : 0;
        __syncthreads();
        sm[tid] += t;
        __syncthreads();
    }
    if (tid < nb) bsum[tid] = sm[tid] - v;
}

__global__ void scan_add(int* __restrict__ offs, int* __restrict__ cursor,
        const int* __restrict__ bsum, int n) {
    int i = blockIdx.x * 256 + threadIdx.x;
    if (i < n) {
        int o = offs[i] + bsum[blockIdx.x];
        offs[i] = o;
        cursor[i] = o;
    }
}

// bucket edges by dst: csr[pos] = src   (cursor[d] ends at end-offset)
__global__ void fill_kernel(const int* __restrict__ src, const int* __restrict__ dst,
        int* __restrict__ cursor, int* __restrict__ csr, int nE) {
    int e = blockIdx.x * blockDim.x + threadIdx.x;
    if (e < nE) {
        int d = dst[e];
        int pos = atomicAdd(&cursor[d], 1);
        csr[pos] = src[e];
    }
}

// H = X[N,128] @ W[128,NOUT]
template<int NOUT, bool RELU_IN>
__global__ __launch_bounds__(256) void gemm_kernel(
    const float* __restrict__ X, const float* __restrict__ W,
    float* __restrict__ H, int N)
{
    constexpr int K = 128, BR = 64, KC = 32, JT = NOUT / 8;
    __shared__ float Ws[KC * NOUT];
    __shared__ float Xs[BR][36];
    const int tid = threadIdx.x;
    const int cg = tid & 7;
    const int rg = tid >> 3;
    const int row0 = blockIdx.x * BR;

    float acc0[JT], acc1[JT];
#pragma unroll
    for (int j = 0; j < JT; ++j) { acc0[j] = 0.f; acc1[j] = 0.f; }

    for (int kc = 0; kc < K; kc += KC) {
        __syncthreads();
        {
            constexpr int TOT4 = KC * NOUT / 4;
            const float4* Wg = (const float4*)(W + kc * NOUT);
            float4* Wl = (float4*)Ws;
            for (int i = tid; i < TOT4; i += 256) Wl[i] = Wg[i];
        }
        {
            for (int i = tid; i < BR * 8; i += 256) {
                int r = i >> 3, c4 = i & 7;
                int gr = row0 + r;
                float4 v = make_float4(0.f, 0.f, 0.f, 0.f);
                if (gr < N) v = *(const float4*)(X + (size_t)gr * K + kc + c4 * 4);
                if (RELU_IN) {
                    v.x = fmaxf(v.x, 0.f); v.y = fmaxf(v.y, 0.f);
                    v.z = fmaxf(v.z, 0.f); v.w = fmaxf(v.w, 0.f);
                }
                *(float4*)&Xs[r][c4 * 4] = v;
            }
        }
        __syncthreads();
#pragma unroll
        for (int k = 0; k < KC; ++k) {
            float x0 = Xs[rg * 2 + 0][k];
            float x1 = Xs[rg * 2 + 1][k];
#pragma unroll
            for (int j4 = 0; j4 < JT / 4; ++j4) {
                float4 w = *(const float4*)&Ws[k * NOUT + cg * JT + j4 * 4];
                acc0[j4*4+0] += x0 * w.x; acc0[j4*4+1] += x0 * w.y;
                acc0[j4*4+2] += x0 * w.z; acc0[j4*4+3] += x0 * w.w;
                acc1[j4*4+0] += x1 * w.x; acc1[j4*4+1] += x1 * w.y;
                acc1[j4*4+2] += x1 * w.z; acc1[j4*4+3] += x1 * w.w;
            }
        }
    }

#pragma unroll
    for (int rr = 0; rr < 2; ++rr) {
        int r = row0 + rg * 2 + rr;
        if (r >= N) continue;
        const float* ac = rr ? acc1 : acc0;
#pragma unroll
        for (int j4 = 0; j4 < JT / 4; ++j4) {
            int col = cg * JT + j4 * 4;
            float4 h;
            h.x = ac[j4*4+0]; h.y = ac[j4*4+1]; h.z = ac[j4*4+2]; h.w = ac[j4*4+3];
            *(float4*)(H + (size_t)r * NOUT + col) = h;
        }
    }
}

// Fused: per block of 16 nodes:
//   a1[n] = relu(b1 + dinv[n]*(dinv[n]*H1[n] + sum_s dinv[s]*H1[s]))   (regs -> LDS)
//   H2[n] = a1[n] @ W2                                                  (W2 staged in LDS)
__global__ __launch_bounds__(512) void agg_gemm_kernel(
        const int* __restrict__ offs, const int* __restrict__ endo,
        const int* __restrict__ csr, const float* __restrict__ dinv,
        const float* __restrict__ H1, const float* __restrict__ b1,
        const float* __restrict__ W2, float* __restrict__ H2, int nNodes)
{
    __shared__ float W2s[128 * 64];   // 32 KB, row-major [k][c]
    __shared__ float a1s[16][128];    // 8 KB
    const int tid = threadIdx.x;

    // cooperative W2 load: 2048 float4 / 512 threads = 4 each
    {
        const float4* Wg = (const float4*)W2;
        float4* Wl = (float4*)W2s;
#pragma unroll
        for (int i = 0; i < 4; ++i) Wl[tid + i * 512] = Wg[tid + i * 512];
    }

    // phase 1: aggregate (32 threads per node, float4 each)
    const int g = tid >> 5, l = tid & 31;
    const int n = blockIdx.x * 16 + g;
    float4 ra = make_float4(0.f, 0.f, 0.f, 0.f);
    if (n < nNodes) {
        const float dn = dinv[n];
        const size_t loff = (size_t)l * 4;
        float4 self = *(const float4*)(H1 + (size_t)n * 128 + loff);
        float4 acc;
        acc.x = dn * self.x; acc.y = dn * self.y; acc.z = dn * self.z; acc.w = dn * self.w;
        int i = offs[n], e0 = endo[n];
        for (; i + 4 <= e0; i += 4) {
            int sa = csr[i], sb = csr[i+1], sc = csr[i+2], sd = csr[i+3];
            float da = dinv[sa], db = dinv[sb], dc = dinv[sc], dd = dinv[sd];
            float4 va = *(const float4*)(H1 + (size_t)sa * 128 + loff);
            float4 vb = *(const float4*)(H1 + (size_t)sb * 128 + loff);
            float4 vc = *(const float4*)(H1 + (size_t)sc * 128 + loff);
            float4 vd = *(const float4*)(H1 + (size_t)sd * 128 + loff);
            acc.x += da*va.x + db*vb.x + dc*vc.x + dd*vd.x;
            acc.y += da*va.y + db*vb.y + dc*vc.y + dd*vd.y;
            acc.z += da*va.z + db*vb.z + dc*vc.z + dd*vd.z;
            acc.w += da*va.w + db*vb.w + dc*vc.w + dd*vd.w;
        }
        for (; i < e0; ++i) {
            int s = csr[i];
            float ds = dinv[s];
            float4 v = *(const float4*)(H1 + (size_t)s * 128 + loff);
            acc.x += ds*v.x; acc.y += ds*v.y; acc.z += ds*v.z; acc.w += ds*v.w;
        }
        float4 bv = *(const float4*)(b1 + loff);
        ra.x = fmaxf(bv.x + dn*acc.x, 0.f);
        ra.y = fmaxf(bv.y + dn*acc.y, 0.f);
        ra.z = fmaxf(bv.z + dn*acc.z, 0.f);
        ra.w = fmaxf(bv.w + dn*acc.w, 0.f);
    }
    *(float4*)&a1s[g][l * 4] = ra;
    __syncthreads();

    // phase 2: h2 = a1s @ W2s ; 16 rows x 64 cols, 2 outputs/thread (float2)
    {
        const int c2 = (tid & 31) * 2;
        const int r  = tid >> 5;
        const int row = blockIdx.x * 16 + r;
        float acc0 = 0.f, acc1 = 0.f;
#pragma unroll
        for (int k = 0; k < 128; k += 4) {
            float4 av = *(const float4*)&a1s[r][k];
            float2 w0 = *(const float2*)&W2s[(k+0)*64 + c2];
            float2 w1 = *(const float2*)&W2s[(k+1)*64 + c2];
            float2 w2 = *(const float2*)&W2s[(k+2)*64 + c2];
            float2 w3 = *(const float2*)&W2s[(k+3)*64 + c2];
            acc0 += av.x*w0.x + av.y*w1.x + av.z*w2.x + av.w*w3.x;
            acc1 += av.x*w0.y + av.y*w1.y + av.z*w2.y + av.w*w3.y;
        }
        if (row < nNodes)
            *(float2*)(H2 + (size_t)row * 64 + c2) = make_float2(acc0, acc1);
    }
}

// Out[n] = bias + dinv[n] * ( dinv[n]*H[n] + sum_{s in csr[n]} dinv[s]*H[s] )
template<int NOUT>
__global__ __launch_bounds__(256) void agg_kernel(
        const int* __restrict__ offs, const int* __restrict__ endo,
        const int* __restrict__ csr, const float* __restrict__ dinv,
        const float* __restrict__ H, const float* __restrict__ bias,
        float* __restrict__ Out, int nNodes)
{
    constexpr int TPN = NOUT / 4;
    constexpr int NPB = 256 / TPN;
    int g = threadIdx.x / TPN;
    int l = threadIdx.x % TPN;
    int n = blockIdx.x * NPB + g;
    if (n >= nNodes) return;
    float dn = dinv[n];
    const size_t loff = (size_t)l * 4;
    float4 self = *(const float4*)(H + (size_t)n * NOUT + loff);
    float4 acc;
    acc.x = dn * self.x; acc.y = dn * self.y; acc.z = dn * self.z; acc.w = dn * self.w;
    int i = offs[n], e0 = endo[n];
    for (; i + 4 <= e0; i += 4) {
        int sa = csr[i], sb = csr[i+1], sc = csr[i+2], sd = csr[i+3];
        float da = dinv[sa], db = dinv[sb], dc = dinv[sc], dd = dinv[sd];
        float4 va = *(const float4*)(H + (size_t)sa * NOUT + loff);
        float4 vb = *(const float4*)(H + (size_t)sb * NOUT + loff);
        float4 vc = *(const float4*)(H + (size_t)sc * NOUT + loff);
        float4 vd = *(const float4*)(H + (size_t)sd * NOUT + loff);
        acc.x += da*va.x + db*vb.x + dc*vc.x + dd*vd.x;
        acc.y += da*va.y + db*vb.y + dc*vc.y + dd*vd.y;
        acc.z += da*va.z + db*vb.z + dc*vc.z + dd*vd.z;
        acc.w += da*va.w + db*vb.w + dc*vc.w + dd*vd.w;
    }
    for (; i < e0; ++i) {
        int s = csr[i];
        float ds = dinv[s];
        float4 v = *(const float4*)(H + (size_t)s * NOUT + loff);
        acc.x += ds*v.x; acc.y += ds*v.y; acc.z += ds*v.z; acc.w += ds*v.w;
    }
    float4 bv = *(const float4*)(bias + loff);
    float4 o;
    o.x = bv.x + dn*acc.x; o.y = bv.y + dn*acc.y;
    o.z = bv.z + dn*acc.z; o.w = bv.w + dn*acc.w;
    *(float4*)(Out + (size_t)n * NOUT + loff) = o;
}

extern "C" void kernel_launch(void* const* d_in, const int* in_sizes, int n_in,
                              void* d_out, int out_size, void* d_ws, size_t ws_size,
                              hipStream_t stream) {
    const float* x  = (const float*)d_in[0];
    const int*   ei = (const int*)d_in[1];
    const float* W1 = (const float*)d_in[2];
    const float* b1 = (const float*)d_in[3];
    const float* W2 = (const float*)d_in[4];
    const float* b2 = (const float*)d_in[5];
    float* out = (float*)d_out;
    char* wsb  = (char*)d_ws;

    const int* srcA = ei;
    const int* dstA = ei + NEDGES;

    int*   deg    = (int*)wsb;                          // 50000
    int*   offs   = deg + NNODES;                       // 50001
    int*   cursor = offs + NNODES + 1;                  // 50000
    float* dinv   = (float*)(cursor + NNODES);          // 50000
    int*   bsum   = (int*)(dinv + NNODES);              // 256
    int*   csr    = bsum + 256;                         // 800000
    float* h1     = (float*)(csr + NEDGES + 3);         // 50000*128 (16B aligned)
    float* h2     = h1 + (size_t)NNODES * 128;          // 50000*64

    hipMemsetAsync(deg, 0, NNODES * sizeof(int), stream);
    deg_kernel<<<(NEDGES + 255) / 256, 256, 0, stream>>>(dstA, deg, NEDGES);
    scan_local<<<NSCB, 256, 0, stream>>>(deg, offs, bsum, dinv, NNODES);
    scan_bsum<<<1, 256, 0, stream>>>(bsum, NSCB);
    scan_add<<<NSCB, 256, 0, stream>>>(offs, cursor, bsum, NNODES);
    fill_kernel<<<(NEDGES + 255) / 256, 256, 0, stream>>>(srcA, dstA, cursor, csr, NEDGES);

    // layer 1 GEMM
    gemm_kernel<128, false><<<(NNODES + 63) / 64, 256, 0, stream>>>(x, W1, h1, NNODES);
    // fused: aggregate layer1 + bias + relu + GEMM2 -> h2
    agg_gemm_kernel<<<(NNODES + 15) / 16, 512, 0, stream>>>(offs, cursor, csr, dinv, h1, b1, W2, h2, NNODES);
    // layer 2 aggregation -> out
    agg_kernel<64><<<(NNODES * 16 + 255) / 256, 256, 0, stream>>>(offs, cursor, csr, dinv, h2, b2, out, NNODES);
}

// Round 5
// 225.931 us; speedup vs baseline: 9.3972x; 1.1975x over previous
//
#include <hip/hip_runtime.h>

#define NNODES 50000
#define NEDGES 800000
#define NSCB ((NNODES + 255) / 256)   // 196 scan blocks

typedef _Float16 half2v __attribute__((ext_vector_type(2)));
typedef _Float16 half4v __attribute__((ext_vector_type(4)));
typedef _Float16 half8v __attribute__((ext_vector_type(8)));

__global__ void deg_kernel(const int* __restrict__ dst, int* __restrict__ deg, int nE) {
    int i = blockIdx.x * blockDim.x + threadIdx.x;
    if (i < nE) atomicAdd(&deg[dst[i]], 1);
}

// local scan (+ fused dinv)
__global__ __launch_bounds__(256) void scan_local(const int* __restrict__ deg,
        int* __restrict__ exc, int* __restrict__ bsum, float* __restrict__ dinv, int n) {
    __shared__ int sm[256];
    int tid = threadIdx.x;
    int i = blockIdx.x * 256 + tid;
    int v = (i < n) ? deg[i] : 0;
    sm[tid] = v;
    __syncthreads();
    for (int off = 1; off < 256; off <<= 1) {
        int t = (tid >= off) ? sm[tid - off] : 0;
        __syncthreads();
        sm[tid] += t;
        __syncthreads();
    }
    if (i < n) {
        exc[i] = sm[tid] - v;
        dinv[i] = 1.0f / sqrtf((float)v + 1.0f);
    }
    if (tid == 255) bsum[blockIdx.x] = sm[255];
}

// each block redundantly scans bsum (196 ints) in LDS, then adds its offset
__global__ __launch_bounds__(256) void scan_addf(int* __restrict__ offs,
        int* __restrict__ cursor, const int* __restrict__ bsum, int n, int nb) {
    __shared__ int sm[256];
    __shared__ int se[256];
    int tid = threadIdx.x;
    int v = (tid < nb) ? bsum[tid] : 0;
    sm[tid] = v;
    __syncthreads();
    for (int off = 1; off < 256; off <<= 1) {
        int t = (tid >= off) ? sm[tid - off] : 0;
        __syncthreads();
        sm[tid] += t;
        __syncthreads();
    }
    se[tid] = sm[tid] - v;
    __syncthreads();
    int boff = se[blockIdx.x];
    int i = blockIdx.x * 256 + tid;
    if (i < n) {
        int o = offs[i] + boff;
        offs[i] = o;
        cursor[i] = o;
    }
}

__global__ void fill_kernel(const int* __restrict__ src, const int* __restrict__ dst,
        int* __restrict__ cursor, int* __restrict__ csr, int nE) {
    int e = blockIdx.x * blockDim.x + threadIdx.x;
    if (e < nE) {
        int d = dst[e];
        int pos = atomicAdd(&cursor[d], 1);
        csr[pos] = src[e];
    }
}

// H1h[N,128] (fp16) = X[N,128](fp32) @ W1[128,128]
__global__ __launch_bounds__(256) void gemm1_kernel(
    const float* __restrict__ X, const float* __restrict__ W,
    _Float16* __restrict__ Hh, int N)
{
    constexpr int K = 128, NOUT = 128, BR = 64, KC = 32, JT = 16;
    __shared__ float Ws[KC * NOUT];
    __shared__ float Xs[BR][36];
    const int tid = threadIdx.x;
    const int cg = tid & 7;
    const int rg = tid >> 3;
    const int row0 = blockIdx.x * BR;

    float acc0[JT], acc1[JT];
#pragma unroll
    for (int j = 0; j < JT; ++j) { acc0[j] = 0.f; acc1[j] = 0.f; }

    for (int kc = 0; kc < K; kc += KC) {
        __syncthreads();
        {
            constexpr int TOT4 = KC * NOUT / 4;
            const float4* Wg = (const float4*)(W + kc * NOUT);
            float4* Wl = (float4*)Ws;
            for (int i = tid; i < TOT4; i += 256) Wl[i] = Wg[i];
        }
        {
            for (int i = tid; i < BR * 8; i += 256) {
                int r = i >> 3, c4 = i & 7;
                int gr = row0 + r;
                float4 v = make_float4(0.f, 0.f, 0.f, 0.f);
                if (gr < N) v = *(const float4*)(X + (size_t)gr * K + kc + c4 * 4);
                *(float4*)&Xs[r][c4 * 4] = v;
            }
        }
        __syncthreads();
#pragma unroll
        for (int k = 0; k < KC; ++k) {
            float x0 = Xs[rg * 2 + 0][k];
            float x1 = Xs[rg * 2 + 1][k];
#pragma unroll
            for (int j4 = 0; j4 < 4; ++j4) {
                float4 w = *(const float4*)&Ws[k * NOUT + cg * JT + j4 * 4];
                acc0[j4*4+0] += x0 * w.x; acc0[j4*4+1] += x0 * w.y;
                acc0[j4*4+2] += x0 * w.z; acc0[j4*4+3] += x0 * w.w;
                acc1[j4*4+0] += x1 * w.x; acc1[j4*4+1] += x1 * w.y;
                acc1[j4*4+2] += x1 * w.z; acc1[j4*4+3] += x1 * w.w;
            }
        }
    }

#pragma unroll
    for (int rr = 0; rr < 2; ++rr) {
        int r = row0 + rg * 2 + rr;
        if (r >= N) continue;
        const float* ac = rr ? acc1 : acc0;
        half8v o0, o1;
#pragma unroll
        for (int j = 0; j < 8; ++j) { o0[j] = (_Float16)ac[j]; o1[j] = (_Float16)ac[8 + j]; }
        _Float16* p = Hh + (size_t)r * 128 + cg * 16;
        *(half8v*)p = o0;
        *(half8v*)(p + 8) = o1;
    }
}

// Fused per wave (2 nodes): aggregate layer1 (fp16 gather) + bias + relu -> LDS,
// then h2 = a1 @ W2 (W2 staged fp32 in LDS). No block barrier after W2 load.
__global__ __launch_bounds__(512) void agg_gemm_kernel(
        const int* __restrict__ offs, const int* __restrict__ endo,
        const int* __restrict__ csr, const float* __restrict__ dinv,
        const _Float16* __restrict__ H1h, const float* __restrict__ b1,
        const float* __restrict__ W2, _Float16* __restrict__ H2h, int nNodes)
{
    __shared__ float W2s[128 * 64];       // 32 KB [k][c]
    __shared__ float a1s[8][2][128];      // 8 KB, per-wave rows
    const int tid = threadIdx.x;

    {   // cooperative W2 load
        const float4* Wg = (const float4*)W2;
        float4* Wl = (float4*)W2s;
#pragma unroll
        for (int i = 0; i < 4; ++i) Wl[tid + i * 512] = Wg[tid + i * 512];
    }
    __syncthreads();   // only barrier: W2s ready for all waves

    const int w  = tid >> 6;          // wave 0..7
    const int g2 = (tid >> 5) & 1;    // node within wave
    const int l  = tid & 31;          // lane within node group
    const int n  = blockIdx.x * 16 + w * 2 + g2;

    // phase 1: aggregate into registers (fp16 gather, fp32 accum)
    float4 ra = make_float4(0.f, 0.f, 0.f, 0.f);
    if (n < nNodes) {
        const float dn = dinv[n];
        const _Float16* Hl = H1h + (size_t)l * 4;
        half4v sv = *(const half4v*)(Hl + (size_t)n * 128);
        float4 acc;
        acc.x = dn * (float)sv[0]; acc.y = dn * (float)sv[1];
        acc.z = dn * (float)sv[2]; acc.w = dn * (float)sv[3];
        int i = offs[n], e0 = endo[n];
        for (; i + 4 <= e0; i += 4) {
            int sa = csr[i], sb = csr[i+1], sc = csr[i+2], sd = csr[i+3];
            float da = dinv[sa], db = dinv[sb], dc = dinv[sc], dd = dinv[sd];
            half4v va = *(const half4v*)(Hl + (size_t)sa * 128);
            half4v vb = *(const half4v*)(Hl + (size_t)sb * 128);
            half4v vc = *(const half4v*)(Hl + (size_t)sc * 128);
            half4v vd = *(const half4v*)(Hl + (size_t)sd * 128);
            acc.x += da*(float)va[0] + db*(float)vb[0] + dc*(float)vc[0] + dd*(float)vd[0];
            acc.y += da*(float)va[1] + db*(float)vb[1] + dc*(float)vc[1] + dd*(float)vd[1];
            acc.z += da*(float)va[2] + db*(float)vb[2] + dc*(float)vc[2] + dd*(float)vd[2];
            acc.w += da*(float)va[3] + db*(float)vb[3] + dc*(float)vc[3] + dd*(float)vd[3];
        }
        for (; i < e0; ++i) {
            int s = csr[i];
            float ds = dinv[s];
            half4v v = *(const half4v*)(Hl + (size_t)s * 128);
            acc.x += ds*(float)v[0]; acc.y += ds*(float)v[1];
            acc.z += ds*(float)v[2]; acc.w += ds*(float)v[3];
        }
        float4 bv = *(const float4*)(b1 + (size_t)l * 4);
        ra.x = fmaxf(bv.x + dn*acc.x, 0.f);
        ra.y = fmaxf(bv.y + dn*acc.y, 0.f);
        ra.z = fmaxf(bv.z + dn*acc.z, 0.f);
        ra.w = fmaxf(bv.w + dn*acc.w, 0.f);
    }
    *(float4*)&a1s[w][g2][l * 4] = ra;
    // wave-local RAW on a1s: wait own wave's LDS writes, no block barrier
    asm volatile("s_waitcnt lgkmcnt(0)" ::: "memory");

    // phase 2: this thread's node n, cols 2l, 2l+1
    {
        const int c2 = l * 2;
        float acc0 = 0.f, acc1 = 0.f;
#pragma unroll
        for (int k = 0; k < 128; k += 4) {
            float4 av = *(const float4*)&a1s[w][g2][k];
            float2 w0 = *(const float2*)&W2s[(k+0)*64 + c2];
            float2 w1 = *(const float2*)&W2s[(k+1)*64 + c2];
            float2 w2 = *(const float2*)&W2s[(k+2)*64 + c2];
            float2 w3 = *(const float2*)&W2s[(k+3)*64 + c2];
            acc0 += av.x*w0.x + av.y*w1.x + av.z*w2.x + av.w*w3.x;
            acc1 += av.x*w0.y + av.y*w1.y + av.z*w2.y + av.w*w3.y;
        }
        if (n < nNodes) {
            half2v o; o[0] = (_Float16)acc0; o[1] = (_Float16)acc1;
            *(half2v*)(H2h + (size_t)n * 64 + c2) = o;
        }
    }
}

// Out[n](fp32) = b2 + dinv[n]*( dinv[n]*H2h[n] + sum_s dinv[s]*H2h[s] ), fp16 gather
__global__ __launch_bounds__(256) void agg2_kernel(
        const int* __restrict__ offs, const int* __restrict__ endo,
        const int* __restrict__ csr, const float* __restrict__ dinv,
        const _Float16* __restrict__ Hh, const float* __restrict__ bias,
        float* __restrict__ Out, int nNodes)
{
    constexpr int TPN = 16;           // 16 lanes x 4 halves = 64 cols
    constexpr int NPB = 256 / TPN;    // 16 nodes/block
    int g = threadIdx.x / TPN;
    int l = threadIdx.x % TPN;
    int n = blockIdx.x * NPB + g;
    if (n >= nNodes) return;
    float dn = dinv[n];
    const _Float16* Hl = Hh + (size_t)l * 4;
    half4v sv = *(const half4v*)(Hl + (size_t)n * 64);
    float4 acc;
    acc.x = dn * (float)sv[0]; acc.y = dn * (float)sv[1];
    acc.z = dn * (float)sv[2]; acc.w = dn * (float)sv[3];
    int i = offs[n], e0 = endo[n];
    for (; i + 4 <= e0; i += 4) {
        int sa = csr[i], sb = csr[i+1], sc = csr[i+2], sd = csr[i+3];
        float da = dinv[sa], db = dinv[sb], dc = dinv[sc], dd = dinv[sd];
        half4v va = *(const half4v*)(Hl + (size_t)sa * 64);
        half4v vb = *(const half4v*)(Hl + (size_t)sb * 64);
        half4v vc = *(const half4v*)(Hl + (size_t)sc * 64);
        half4v vd = *(const half4v*)(Hl + (size_t)sd * 64);
        acc.x += da*(float)va[0] + db*(float)vb[0] + dc*(float)vc[0] + dd*(float)vd[0];
        acc.y += da*(float)va[1] + db*(float)vb[1] + dc*(float)vc[1] + dd*(float)vd[1];
        acc.z += da*(float)va[2] + db*(float)vb[2] + dc*(float)vc[2] + dd*(float)vd[2];
        acc.w += da*(float)va[3] + db*(float)vb[3] + dc*(float)vc[3] + dd*(float)vd[3];
    }
    for (; i < e0; ++i) {
        int s = csr[i];
        float ds = dinv[s];
        half4v v = *(const half4v*)(Hl + (size_t)s * 64);
        acc.x += ds*(float)v[0]; acc.y += ds*(float)v[1];
        acc.z += ds*(float)v[2]; acc.w += ds*(float)v[3];
    }
    float4 bv = *(const float4*)(bias + (size_t)l * 4);
    float4 o;
    o.x = bv.x + dn*acc.x; o.y = bv.y + dn*acc.y;
    o.z = bv.z + dn*acc.z; o.w = bv.w + dn*acc.w;
    *(float4*)(Out + (size_t)n * 64 + (size_t)l * 4) = o;
}

extern "C" void kernel_launch(void* const* d_in, const int* in_sizes, int n_in,
                              void* d_out, int out_size, void* d_ws, size_t ws_size,
                              hipStream_t stream) {
    const float* x  = (const float*)d_in[0];
    const int*   ei = (const int*)d_in[1];
    const float* W1 = (const float*)d_in[2];
    const float* b1 = (const float*)d_in[3];
    const float* W2 = (const float*)d_in[4];
    const float* b2 = (const float*)d_in[5];
    float* out = (float*)d_out;
    char* wsb  = (char*)d_ws;

    const int* srcA = ei;
    const int* dstA = ei + NEDGES;

    int*   deg    = (int*)wsb;                          // 50000
    int*   offs   = deg + NNODES;                       // 50001
    int*   cursor = offs + NNODES + 1;                  // 50000
    float* dinv   = (float*)(cursor + NNODES);          // 50000
    int*   bsum   = (int*)(dinv + NNODES);              // 256
    int*   csr    = bsum + 256;                         // 800000
    _Float16* h1h = (_Float16*)(csr + NEDGES + 3);      // 50000*128 fp16 (16B aligned)
    _Float16* h2h = h1h + (size_t)NNODES * 128;         // 50000*64 fp16

    hipMemsetAsync(deg, 0, NNODES * sizeof(int), stream);
    deg_kernel<<<(NEDGES + 255) / 256, 256, 0, stream>>>(dstA, deg, NEDGES);
    scan_local<<<NSCB, 256, 0, stream>>>(deg, offs, bsum, dinv, NNODES);
    scan_addf<<<NSCB, 256, 0, stream>>>(offs, cursor, bsum, NNODES, NSCB);
    fill_kernel<<<(NEDGES + 255) / 256, 256, 0, stream>>>(srcA, dstA, cursor, csr, NEDGES);

    gemm1_kernel<<<(NNODES + 63) / 64, 256, 0, stream>>>(x, W1, h1h, NNODES);
    agg_gemm_kernel<<<(NNODES + 15) / 16, 512, 0, stream>>>(offs, cursor, csr, dinv, h1h, b1, W2, h2h, NNODES);
    agg2_kernel<<<(NNODES * 16 + 255) / 256, 256, 0, stream>>>(offs, cursor, csr, dinv, h2h, b2, out, NNODES);
}

// Round 6
// 201.104 us; speedup vs baseline: 10.5573x; 1.1235x over previous
//
#include <hip/hip_runtime.h>

#define NNODES 50000
#define NEDGES 800000
#define NSCB ((NNODES + 255) / 256)   // 196 scan blocks

typedef _Float16 half4v __attribute__((ext_vector_type(4)));
typedef _Float16 half8v __attribute__((ext_vector_type(8)));
typedef float floatx4 __attribute__((ext_vector_type(4)));

__global__ void deg_kernel(const int* __restrict__ dst, int* __restrict__ deg, int nE) {
    int i = blockIdx.x * blockDim.x + threadIdx.x;
    if (i < nE) atomicAdd(&deg[dst[i]], 1);
}

// local scan (+ fused dinv)
__global__ __launch_bounds__(256) void scan_local(const int* __restrict__ deg,
        int* __restrict__ exc, int* __restrict__ bsum, float* __restrict__ dinv, int n) {
    __shared__ int sm[256];
    int tid = threadIdx.x;
    int i = blockIdx.x * 256 + tid;
    int v = (i < n) ? deg[i] : 0;
    sm[tid] = v;
    __syncthreads();
    for (int off = 1; off < 256; off <<= 1) {
        int t = (tid >= off) ? sm[tid - off] : 0;
        __syncthreads();
        sm[tid] += t;
        __syncthreads();
    }
    if (i < n) {
        exc[i] = sm[tid] - v;
        dinv[i] = 1.0f / sqrtf((float)v + 1.0f);
    }
    if (tid == 255) bsum[blockIdx.x] = sm[255];
}

// each block redundantly scans bsum in LDS, then adds its offset
__global__ __launch_bounds__(256) void scan_addf(int* __restrict__ offs,
        int* __restrict__ cursor, const int* __restrict__ bsum, int n, int nb) {
    __shared__ int sm[256];
    __shared__ int se[256];
    int tid = threadIdx.x;
    int v = (tid < nb) ? bsum[tid] : 0;
    sm[tid] = v;
    __syncthreads();
    for (int off = 1; off < 256; off <<= 1) {
        int t = (tid >= off) ? sm[tid - off] : 0;
        __syncthreads();
        sm[tid] += t;
        __syncthreads();
    }
    se[tid] = sm[tid] - v;
    __syncthreads();
    int boff = se[blockIdx.x];
    int i = blockIdx.x * 256 + tid;
    if (i < n) {
        int o = offs[i] + boff;
        offs[i] = o;
        cursor[i] = o;
    }
}

__global__ void fill_kernel(const int* __restrict__ src, const int* __restrict__ dst,
        int* __restrict__ cursor, int* __restrict__ csr, int nE) {
    int e = blockIdx.x * blockDim.x + threadIdx.x;
    if (e < nE) {
        int d = dst[e];
        int pos = atomicAdd(&cursor[d], 1);
        csr[pos] = src[e];
    }
}

// h1w[r,:] = dinv[r] * (X[r,:] @ W1)  via fp16 MFMA, fp16 output.
// Block: 256 thr = 4 waves; 64 rows. Wave grid 2Mx2N; per wave 2 mtiles x 4 ntiles.
__global__ __launch_bounds__(256) void gemm1_mfma(
    const float* __restrict__ X, const float* __restrict__ W,
    const float* __restrict__ dinv, _Float16* __restrict__ H, int N)
{
    __shared__ _Float16 outs[64][128];   // 16 KB bounce
    const int tid  = threadIdx.x;
    const int lane = tid & 63;
    const int wv   = tid >> 6;
    const int mh   = wv >> 1;            // rows mh*32..
    const int nh   = wv & 1;             // cols nh*64..
    const int t    = lane & 15;
    const int g    = lane >> 4;
    const int row0 = blockIdx.x * 64;

    // B preload: 16 fragments, 8 strided dwords each (W1 is L2-resident)
    half8v bf[4][4];
#pragma unroll
    for (int s = 0; s < 4; ++s) {
#pragma unroll
        for (int nt = 0; nt < 4; ++nt) {
            const float* wp = W + (size_t)(s * 32 + g * 8) * 128 + nh * 64 + nt * 16 + t;
            half8v h;
#pragma unroll
            for (int i = 0; i < 8; ++i) h[i] = (_Float16)wp[(size_t)i * 128];
            bf[s][nt] = h;
        }
    }

    floatx4 acc[2][4];
#pragma unroll
    for (int mt = 0; mt < 2; ++mt)
#pragma unroll
        for (int nt = 0; nt < 4; ++nt) acc[mt][nt] = (floatx4){0.f, 0.f, 0.f, 0.f};

#pragma unroll
    for (int s = 0; s < 4; ++s) {
#pragma unroll
        for (int mt = 0; mt < 2; ++mt) {
            int r = row0 + mh * 32 + mt * 16 + t;
            if (r > N - 1) r = N - 1;
            const float* xp = X + (size_t)r * 128 + s * 32 + g * 8;
            float4 x0 = *(const float4*)xp;
            float4 x1 = *(const float4*)(xp + 4);
            half8v af;
            af[0] = (_Float16)x0.x; af[1] = (_Float16)x0.y;
            af[2] = (_Float16)x0.z; af[3] = (_Float16)x0.w;
            af[4] = (_Float16)x1.x; af[5] = (_Float16)x1.y;
            af[6] = (_Float16)x1.z; af[7] = (_Float16)x1.w;
#pragma unroll
            for (int nt = 0; nt < 4; ++nt)
                acc[mt][nt] = __builtin_amdgcn_mfma_f32_16x16x32_f16(af, bf[s][nt], acc[mt][nt], 0, 0, 0);
        }
    }

    // epilogue: scale by dinv, fp16, LDS bounce (C/D: row=(l>>4)*4+r, col=l&15)
#pragma unroll
    for (int mt = 0; mt < 2; ++mt) {
#pragma unroll
        for (int r4 = 0; r4 < 4; ++r4) {
            int lrow = mh * 32 + mt * 16 + g * 4 + r4;
            int grow = row0 + lrow;
            if (grow > N - 1) grow = N - 1;
            float dv = dinv[grow];
#pragma unroll
            for (int nt = 0; nt < 4; ++nt)
                outs[lrow][nh * 64 + nt * 16 + t] = (_Float16)(acc[mt][nt][r4] * dv);
        }
    }
    __syncthreads();
    {
        int lrow = tid >> 2, c0 = (tid & 3) * 32;
        int grow = row0 + lrow;
        if (grow < N) {
            const half8v* srcp = (const half8v*)&outs[lrow][c0];
            half8v* dstp = (half8v*)(H + (size_t)grow * 128 + c0);
#pragma unroll
            for (int i = 0; i < 4; ++i) dstp[i] = srcp[i];
        }
    }
}

// Fused: a1[n] = relu(b1 + dinv[n]*(h1w[n] + sum_s h1w[s]))  (16 lanes/node, 16B loads)
//        h2w[n] = dinv[n] * (a1[n] @ W2)   (W2 staged fp16 in LDS; wave-local phase link)
__global__ __launch_bounds__(512) void agg_gemm_kernel(
        const int* __restrict__ offs, const int* __restrict__ endo,
        const int* __restrict__ csr, const float* __restrict__ dinv,
        const _Float16* __restrict__ H1h, const float* __restrict__ b1,
        const float* __restrict__ W2, _Float16* __restrict__ H2h, int nNodes)
{
    __shared__ _Float16 W2s[128 * 64];    // 16 KB [k][c]
    __shared__ float a1s[32][128];        // 16 KB
    const int tid = threadIdx.x;

    {   // cooperative W2 load + fp16 convert
        const float4* Wg = (const float4*)W2;
#pragma unroll
        for (int i = 0; i < 4; ++i) {
            int idx = tid + i * 512;
            float4 fv = Wg[idx];
            half4v hv;
            hv[0] = (_Float16)fv.x; hv[1] = (_Float16)fv.y;
            hv[2] = (_Float16)fv.z; hv[3] = (_Float16)fv.w;
            *(half4v*)&W2s[idx * 4] = hv;
        }
    }
    __syncthreads();

    const int w = tid >> 6, lane = tid & 63;
    const int q = lane >> 4, u = lane & 15;   // 4 nodes/wave, 16 lanes/node
    const int nloc = w * 4 + q;
    const int nid = blockIdx.x * 32 + nloc;

    float a0 = 0.f, a1_ = 0.f, a2 = 0.f, a3 = 0.f, a4 = 0.f, a5 = 0.f, a6 = 0.f, a7 = 0.f;
    float dn = 0.f;
    if (nid < nNodes) {
        dn = dinv[nid];
        const _Float16* Hl = H1h + u * 8;
        half8v sv = *(const half8v*)(Hl + (size_t)nid * 128);
        a0 = (float)sv[0]; a1_ = (float)sv[1]; a2 = (float)sv[2]; a3 = (float)sv[3];
        a4 = (float)sv[4]; a5 = (float)sv[5]; a6 = (float)sv[6]; a7 = (float)sv[7];
        int i = offs[nid], e0 = endo[nid];
        for (; i + 4 <= e0; i += 4) {
            int sa = csr[i], sb = csr[i + 1], sc = csr[i + 2], sd = csr[i + 3];
            half8v va = *(const half8v*)(Hl + (size_t)sa * 128);
            half8v vb = *(const half8v*)(Hl + (size_t)sb * 128);
            half8v vc = *(const half8v*)(Hl + (size_t)sc * 128);
            half8v vd = *(const half8v*)(Hl + (size_t)sd * 128);
            a0 += (float)va[0] + (float)vb[0] + (float)vc[0] + (float)vd[0];
            a1_ += (float)va[1] + (float)vb[1] + (float)vc[1] + (float)vd[1];
            a2 += (float)va[2] + (float)vb[2] + (float)vc[2] + (float)vd[2];
            a3 += (float)va[3] + (float)vb[3] + (float)vc[3] + (float)vd[3];
            a4 += (float)va[4] + (float)vb[4] + (float)vc[4] + (float)vd[4];
            a5 += (float)va[5] + (float)vb[5] + (float)vc[5] + (float)vd[5];
            a6 += (float)va[6] + (float)vb[6] + (float)vc[6] + (float)vd[6];
            a7 += (float)va[7] + (float)vb[7] + (float)vc[7] + (float)vd[7];
        }
        for (; i < e0; ++i) {
            int s = csr[i];
            half8v v = *(const half8v*)(Hl + (size_t)s * 128);
            a0 += (float)v[0]; a1_ += (float)v[1]; a2 += (float)v[2]; a3 += (float)v[3];
            a4 += (float)v[4]; a5 += (float)v[5]; a6 += (float)v[6]; a7 += (float)v[7];
        }
        float4 b0 = *(const float4*)(b1 + u * 8);
        float4 b4 = *(const float4*)(b1 + u * 8 + 4);
        a0 = fmaxf(b0.x + dn * a0, 0.f); a1_ = fmaxf(b0.y + dn * a1_, 0.f);
        a2 = fmaxf(b0.z + dn * a2, 0.f); a3 = fmaxf(b0.w + dn * a3, 0.f);
        a4 = fmaxf(b4.x + dn * a4, 0.f); a5 = fmaxf(b4.y + dn * a5, 0.f);
        a6 = fmaxf(b4.z + dn * a6, 0.f); a7 = fmaxf(b4.w + dn * a7, 0.f);
    }
    *(float4*)&a1s[nloc][u * 8]     = make_float4(a0, a1_, a2, a3);
    *(float4*)&a1s[nloc][u * 8 + 4] = make_float4(a4, a5, a6, a7);
    // phase 2 reads only own-wave rows; wave-local RAW -> waitcnt suffices
    asm volatile("s_waitcnt lgkmcnt(0)" ::: "memory");

    // phase 2: node nloc, cols u*4..u*4+3
    {
        float o0 = 0.f, o1 = 0.f, o2 = 0.f, o3 = 0.f;
#pragma unroll 4
        for (int k4 = 0; k4 < 32; ++k4) {
            floatx4 av = *(const floatx4*)&a1s[nloc][k4 * 4];
#pragma unroll
            for (int j = 0; j < 4; ++j) {
                half4v wv4 = *(const half4v*)&W2s[(k4 * 4 + j) * 64 + u * 4];
                float a = av[j];
                o0 += a * (float)wv4[0]; o1 += a * (float)wv4[1];
                o2 += a * (float)wv4[2]; o3 += a * (float)wv4[3];
            }
        }
        if (nid < nNodes) {
            half4v o;
            o[0] = (_Float16)(dn * o0); o[1] = (_Float16)(dn * o1);
            o[2] = (_Float16)(dn * o2); o[3] = (_Float16)(dn * o3);
            *(half4v*)(H2h + (size_t)nid * 64 + u * 4) = o;
        }
    }
}

// out[n] = b2 + dinv[n]*( h2w[n] + sum_s h2w[s] ), 8 lanes/node, 16B loads
__global__ __launch_bounds__(256) void agg2_kernel(
        const int* __restrict__ offs, const int* __restrict__ endo,
        const int* __restrict__ csr, const float* __restrict__ dinv,
        const _Float16* __restrict__ Hh, const float* __restrict__ bias,
        float* __restrict__ Out, int nNodes)
{
    const int tid = threadIdx.x;
    const int w = tid >> 6, lane = tid & 63;
    const int q = lane >> 3, u = lane & 7;    // 8 nodes/wave, 8 lanes/node
    const int n = blockIdx.x * 32 + w * 8 + q;
    if (n >= nNodes) return;
    float dn = dinv[n];
    const _Float16* Hl = Hh + u * 8;
    half8v sv = *(const half8v*)(Hl + (size_t)n * 64);
    float a0 = (float)sv[0], a1_ = (float)sv[1], a2 = (float)sv[2], a3 = (float)sv[3];
    float a4 = (float)sv[4], a5 = (float)sv[5], a6 = (float)sv[6], a7 = (float)sv[7];
    int i = offs[n], e0 = endo[n];
    for (; i + 4 <= e0; i += 4) {
        int sa = csr[i], sb = csr[i + 1], sc = csr[i + 2], sd = csr[i + 3];
        half8v va = *(const half8v*)(Hl + (size_t)sa * 64);
        half8v vb = *(const half8v*)(Hl + (size_t)sb * 64);
        half8v vc = *(const half8v*)(Hl + (size_t)sc * 64);
        half8v vd = *(const half8v*)(Hl + (size_t)sd * 64);
        a0 += (float)va[0] + (float)vb[0] + (float)vc[0] + (float)vd[0];
        a1_ += (float)va[1] + (float)vb[1] + (float)vc[1] + (float)vd[1];
        a2 += (float)va[2] + (float)vb[2] + (float)vc[2] + (float)vd[2];
        a3 += (float)va[3] + (float)vb[3] + (float)vc[3] + (float)vd[3];
        a4 += (float)va[4] + (float)vb[4] + (float)vc[4] + (float)vd[4];
        a5 += (float)va[5] + (float)vb[5] + (float)vc[5] + (float)vd[5];
        a6 += (float)va[6] + (float)vb[6] + (float)vc[6] + (float)vd[6];
        a7 += (float)va[7] + (float)vb[7] + (float)vc[7] + (float)vd[7];
    }
    for (; i < e0; ++i) {
        int s = csr[i];
        half8v v = *(const half8v*)(Hl + (size_t)s * 64);
        a0 += (float)v[0]; a1_ += (float)v[1]; a2 += (float)v[2]; a3 += (float)v[3];
        a4 += (float)v[4]; a5 += (float)v[5]; a6 += (float)v[6]; a7 += (float)v[7];
    }
    float4 b0 = *(const float4*)(bias + u * 8);
    float4 b4 = *(const float4*)(bias + u * 8 + 4);
    float* op = Out + (size_t)n * 64 + u * 8;
    *(float4*)op       = make_float4(b0.x + dn * a0, b0.y + dn * a1_, b0.z + dn * a2, b0.w + dn * a3);
    *(float4*)(op + 4) = make_float4(b4.x + dn * a4, b4.y + dn * a5, b4.z + dn * a6, b4.w + dn * a7);
}

extern "C" void kernel_launch(void* const* d_in, const int* in_sizes, int n_in,
                              void* d_out, int out_size, void* d_ws, size_t ws_size,
                              hipStream_t stream) {
    const float* x  = (const float*)d_in[0];
    const int*   ei = (const int*)d_in[1];
    const float* W1 = (const float*)d_in[2];
    const float* b1 = (const float*)d_in[3];
    const float* W2 = (const float*)d_in[4];
    const float* b2 = (const float*)d_in[5];
    float* out = (float*)d_out;
    char* wsb  = (char*)d_ws;

    const int* srcA = ei;
    const int* dstA = ei + NEDGES;

    int*   deg    = (int*)wsb;                          // 50000
    int*   offs   = deg + NNODES;                       // 50001
    int*   cursor = offs + NNODES + 1;                  // 50000
    float* dinv   = (float*)(cursor + NNODES);          // 50000
    int*   bsum   = (int*)(dinv + NNODES);              // 256
    int*   csr    = bsum + 256;                         // 800000
    _Float16* h1h = (_Float16*)(csr + NEDGES + 3);      // 50000*128 fp16 (16B aligned)
    _Float16* h2h = h1h + (size_t)NNODES * 128;         // 50000*64 fp16

    hipMemsetAsync(deg, 0, NNODES * sizeof(int), stream);
    deg_kernel<<<(NEDGES + 255) / 256, 256, 0, stream>>>(dstA, deg, NEDGES);
    scan_local<<<NSCB, 256, 0, stream>>>(deg, offs, bsum, dinv, NNODES);
    scan_addf<<<NSCB, 256, 0, stream>>>(offs, cursor, bsum, NNODES, NSCB);
    fill_kernel<<<(NEDGES + 255) / 256, 256, 0, stream>>>(srcA, dstA, cursor, csr, NEDGES);

    // h1w = dinv * (x @ W1)  (fp16 MFMA)
    gemm1_mfma<<<(NNODES + 63) / 64, 256, 0, stream>>>(x, W1, dinv, h1h, NNODES);
    // a1 = relu(b1 + dinv*(sum h1w)); h2w = dinv * (a1 @ W2)
    agg_gemm_kernel<<<(NNODES + 31) / 32, 512, 0, stream>>>(offs, cursor, csr, dinv, h1h, b1, W2, h2h, NNODES);
    // out = b2 + dinv*(sum h2w)
    agg2_kernel<<<(NNODES + 31) / 32, 256, 0, stream>>>(offs, cursor, csr, dinv, h2h, b2, out, NNODES);
}

// Round 7
// 174.781 us; speedup vs baseline: 12.1473x; 1.1506x over previous
//
#include <hip/hip_runtime.h>

#define NNODES 50000
#define NEDGES 800000
#define NSCB ((NNODES + 255) / 256)   // 196 scan blocks

typedef _Float16 half4v __attribute__((ext_vector_type(4)));
typedef _Float16 half8v __attribute__((ext_vector_type(8)));
typedef float floatx4 __attribute__((ext_vector_type(4)));

__global__ void deg_kernel(const int* __restrict__ dst, int* __restrict__ deg, int nE) {
    int i = blockIdx.x * blockDim.x + threadIdx.x;
    if (i < nE) atomicAdd(&deg[dst[i]], 1);
}

// local scan (+ fused dinv)
__global__ __launch_bounds__(256) void scan_local(const int* __restrict__ deg,
        int* __restrict__ exc, int* __restrict__ bsum, float* __restrict__ dinv, int n) {
    __shared__ int sm[256];
    int tid = threadIdx.x;
    int i = blockIdx.x * 256 + tid;
    int v = (i < n) ? deg[i] : 0;
    sm[tid] = v;
    __syncthreads();
    for (int off = 1; off < 256; off <<= 1) {
        int t = (tid >= off) ? sm[tid - off] : 0;
        __syncthreads();
        sm[tid] += t;
        __syncthreads();
    }
    if (i < n) {
        exc[i] = sm[tid] - v;
        dinv[i] = 1.0f / sqrtf((float)v + 1.0f);
    }
    if (tid == 255) bsum[blockIdx.x] = sm[255];
}

// each block redundantly scans bsum in LDS, then adds its offset
__global__ __launch_bounds__(256) void scan_addf(int* __restrict__ offs,
        int* __restrict__ cursor, const int* __restrict__ bsum, int n, int nb) {
    __shared__ int sm[256];
    __shared__ int se[256];
    int tid = threadIdx.x;
    int v = (tid < nb) ? bsum[tid] : 0;
    sm[tid] = v;
    __syncthreads();
    for (int off = 1; off < 256; off <<= 1) {
        int t = (tid >= off) ? sm[tid - off] : 0;
        __syncthreads();
        sm[tid] += t;
        __syncthreads();
    }
    se[tid] = sm[tid] - v;
    __syncthreads();
    int boff = se[blockIdx.x];
    int i = blockIdx.x * 256 + tid;
    if (i < n) {
        int o = offs[i] + boff;
        offs[i] = o;
        cursor[i] = o;
    }
}

__global__ void fill_kernel(const int* __restrict__ src, const int* __restrict__ dst,
        int* __restrict__ cursor, unsigned short* __restrict__ csr, int nE) {
    int e = blockIdx.x * blockDim.x + threadIdx.x;
    if (e < nE) {
        int d = dst[e];
        int pos = atomicAdd(&cursor[d], 1);
        csr[pos] = (unsigned short)src[e];
    }
}

// h1w[r,:] = dinv[r] * (X[r,:] @ W1)  via fp16 MFMA, fp16 output.
__global__ __launch_bounds__(256) void gemm1_mfma(
    const float* __restrict__ X, const float* __restrict__ W,
    const float* __restrict__ dinv, _Float16* __restrict__ H, int N)
{
    __shared__ _Float16 outs[64][136];   // padded: conflict-free epilogue
    const int tid  = threadIdx.x;
    const int lane = tid & 63;
    const int wv   = tid >> 6;
    const int mh   = wv >> 1;
    const int nh   = wv & 1;
    const int t    = lane & 15;
    const int g    = lane >> 4;
    const int row0 = blockIdx.x * 64;

    half8v bf[4][4];
#pragma unroll
    for (int s = 0; s < 4; ++s) {
#pragma unroll
        for (int nt = 0; nt < 4; ++nt) {
            const float* wp = W + (size_t)(s * 32 + g * 8) * 128 + nh * 64 + nt * 16 + t;
            half8v h;
#pragma unroll
            for (int i = 0; i < 8; ++i) h[i] = (_Float16)wp[(size_t)i * 128];
            bf[s][nt] = h;
        }
    }

    floatx4 acc[2][4];
#pragma unroll
    for (int mt = 0; mt < 2; ++mt)
#pragma unroll
        for (int nt = 0; nt < 4; ++nt) acc[mt][nt] = (floatx4){0.f, 0.f, 0.f, 0.f};

#pragma unroll
    for (int s = 0; s < 4; ++s) {
#pragma unroll
        for (int mt = 0; mt < 2; ++mt) {
            int r = row0 + mh * 32 + mt * 16 + t;
            if (r > N - 1) r = N - 1;
            const float* xp = X + (size_t)r * 128 + s * 32 + g * 8;
            float4 x0 = *(const float4*)xp;
            float4 x1 = *(const float4*)(xp + 4);
            half8v af;
            af[0] = (_Float16)x0.x; af[1] = (_Float16)x0.y;
            af[2] = (_Float16)x0.z; af[3] = (_Float16)x0.w;
            af[4] = (_Float16)x1.x; af[5] = (_Float16)x1.y;
            af[6] = (_Float16)x1.z; af[7] = (_Float16)x1.w;
#pragma unroll
            for (int nt = 0; nt < 4; ++nt)
                acc[mt][nt] = __builtin_amdgcn_mfma_f32_16x16x32_f16(af, bf[s][nt], acc[mt][nt], 0, 0, 0);
        }
    }

#pragma unroll
    for (int mt = 0; mt < 2; ++mt) {
#pragma unroll
        for (int r4 = 0; r4 < 4; ++r4) {
            int lrow = mh * 32 + mt * 16 + g * 4 + r4;
            int grow = row0 + lrow;
            if (grow > N - 1) grow = N - 1;
            float dv = dinv[grow];
#pragma unroll
            for (int nt = 0; nt < 4; ++nt)
                outs[lrow][nh * 64 + nt * 16 + t] = (_Float16)(acc[mt][nt][r4] * dv);
        }
    }
    __syncthreads();
    {
        int lrow = tid >> 2, c0 = (tid & 3) * 32;
        int grow = row0 + lrow;
        if (grow < N) {
            const half8v* srcp = (const half8v*)&outs[lrow][c0];
            half8v* dstp = (half8v*)(H + (size_t)grow * 128 + c0);
#pragma unroll
            for (int i = 0; i < 4; ++i) dstp[i] = srcp[i];
        }
    }
}

// Fused: a1[n] = relu(b1 + dinv[n]*(h1w[n] + sum_s h1w[s]))  (16 lanes/node)
//        h2w[n] = dinv[n] * (a1[n] @ W2)   (W2 fp16 in LDS; wave-local phase link)
__global__ __launch_bounds__(512) void agg_gemm_kernel(
        const int* __restrict__ offs, const int* __restrict__ endo,
        const unsigned short* __restrict__ csr, const float* __restrict__ dinv,
        const _Float16* __restrict__ H1h, const float* __restrict__ b1,
        const float* __restrict__ W2, _Float16* __restrict__ H2h, int nNodes)
{
    __shared__ _Float16 W2s[128 * 64];    // 16 KB [k][c]
    __shared__ float a1s[32][132];        // padded rows: +4 banks/row
    const int tid = threadIdx.x;

    {   // cooperative W2 load + fp16 convert
        const float4* Wg = (const float4*)W2;
#pragma unroll
        for (int i = 0; i < 4; ++i) {
            int idx = tid + i * 512;
            float4 fv = Wg[idx];
            half4v hv;
            hv[0] = (_Float16)fv.x; hv[1] = (_Float16)fv.y;
            hv[2] = (_Float16)fv.z; hv[3] = (_Float16)fv.w;
            *(half4v*)&W2s[idx * 4] = hv;
        }
    }
    __syncthreads();

    const int w = tid >> 6, lane = tid & 63;
    const int q = lane >> 4, u = lane & 15;   // 4 nodes/wave, 16 lanes/node
    const int nloc = w * 4 + q;
    const int nid = blockIdx.x * 32 + nloc;

    float a0 = 0.f, a1_ = 0.f, a2 = 0.f, a3 = 0.f, a4 = 0.f, a5 = 0.f, a6 = 0.f, a7 = 0.f;
    float dn = 0.f;
    if (nid < nNodes) {
        dn = dinv[nid];
        const _Float16* Hl = H1h + u * 8;
        half8v sv = *(const half8v*)(Hl + (size_t)nid * 128);
        a0 = (float)sv[0]; a1_ = (float)sv[1]; a2 = (float)sv[2]; a3 = (float)sv[3];
        a4 = (float)sv[4]; a5 = (float)sv[5]; a6 = (float)sv[6]; a7 = (float)sv[7];
        int i = offs[nid], e0 = endo[nid];
        for (; i + 4 <= e0; i += 4) {
            int sa = csr[i], sb = csr[i + 1], sc = csr[i + 2], sd = csr[i + 3];
            half8v va = *(const half8v*)(Hl + (size_t)sa * 128);
            half8v vb = *(const half8v*)(Hl + (size_t)sb * 128);
            half8v vc = *(const half8v*)(Hl + (size_t)sc * 128);
            half8v vd = *(const half8v*)(Hl + (size_t)sd * 128);
            a0 += (float)va[0] + (float)vb[0] + (float)vc[0] + (float)vd[0];
            a1_ += (float)va[1] + (float)vb[1] + (float)vc[1] + (float)vd[1];
            a2 += (float)va[2] + (float)vb[2] + (float)vc[2] + (float)vd[2];
            a3 += (float)va[3] + (float)vb[3] + (float)vc[3] + (float)vd[3];
            a4 += (float)va[4] + (float)vb[4] + (float)vc[4] + (float)vd[4];
            a5 += (float)va[5] + (float)vb[5] + (float)vc[5] + (float)vd[5];
            a6 += (float)va[6] + (float)vb[6] + (float)vc[6] + (float)vd[6];
            a7 += (float)va[7] + (float)vb[7] + (float)vc[7] + (float)vd[7];
        }
        for (; i < e0; ++i) {
            int s = csr[i];
            half8v v = *(const half8v*)(Hl + (size_t)s * 128);
            a0 += (float)v[0]; a1_ += (float)v[1]; a2 += (float)v[2]; a3 += (float)v[3];
            a4 += (float)v[4]; a5 += (float)v[5]; a6 += (float)v[6]; a7 += (float)v[7];
        }
        float4 b0 = *(const float4*)(b1 + u * 8);
        float4 b4 = *(const float4*)(b1 + u * 8 + 4);
        a0 = fmaxf(b0.x + dn * a0, 0.f); a1_ = fmaxf(b0.y + dn * a1_, 0.f);
        a2 = fmaxf(b0.z + dn * a2, 0.f); a3 = fmaxf(b0.w + dn * a3, 0.f);
        a4 = fmaxf(b4.x + dn * a4, 0.f); a5 = fmaxf(b4.y + dn * a5, 0.f);
        a6 = fmaxf(b4.z + dn * a6, 0.f); a7 = fmaxf(b4.w + dn * a7, 0.f);
    }
    *(float4*)&a1s[nloc][u * 8]     = make_float4(a0, a1_, a2, a3);
    *(float4*)&a1s[nloc][u * 8 + 4] = make_float4(a4, a5, a6, a7);
    // phase 2 reads only own-wave rows; wave-local RAW -> waitcnt suffices
    asm volatile("s_waitcnt lgkmcnt(0)" ::: "memory");

    // phase 2: node nloc, cols u*4..u*4+3
    {
        float o0 = 0.f, o1 = 0.f, o2 = 0.f, o3 = 0.f;
#pragma unroll 4
        for (int k4 = 0; k4 < 32; ++k4) {
            floatx4 av = *(const floatx4*)&a1s[nloc][k4 * 4];
#pragma unroll
            for (int j = 0; j < 4; ++j) {
                half4v wv4 = *(const half4v*)&W2s[(k4 * 4 + j) * 64 + u * 4];
                float a = av[j];
                o0 += a * (float)wv4[0]; o1 += a * (float)wv4[1];
                o2 += a * (float)wv4[2]; o3 += a * (float)wv4[3];
            }
        }
        if (nid < nNodes) {
            half4v o;
            o[0] = (_Float16)(dn * o0); o[1] = (_Float16)(dn * o1);
            o[2] = (_Float16)(dn * o2); o[3] = (_Float16)(dn * o3);
            *(half4v*)(H2h + (size_t)nid * 64 + u * 4) = o;
        }
    }
}

// out[n] = b2 + dinv[n]*( h2w[n] + sum_s h2w[s] ), 8 lanes/node, 16B loads
__global__ __launch_bounds__(256) void agg2_kernel(
        const int* __restrict__ offs, const int* __restrict__ endo,
        const unsigned short* __restrict__ csr, const float* __restrict__ dinv,
        const _Float16* __restrict__ Hh, const float* __restrict__ bias,
        float* __restrict__ Out, int nNodes)
{
    const int tid = threadIdx.x;
    const int w = tid >> 6, lane = tid & 63;
    const int q = lane >> 3, u = lane & 7;    // 8 nodes/wave, 8 lanes/node
    const int n = blockIdx.x * 32 + w * 8 + q;
    if (n >= nNodes) return;
    float dn = dinv[n];
    const _Float16* Hl = Hh + u * 8;
    half8v sv = *(const half8v*)(Hl + (size_t)n * 64);
    float a0 = (float)sv[0], a1_ = (float)sv[1], a2 = (float)sv[2], a3 = (float)sv[3];
    float a4 = (float)sv[4], a5 = (float)sv[5], a6 = (float)sv[6], a7 = (float)sv[7];
    int i = offs[n], e0 = endo[n];
    for (; i + 4 <= e0; i += 4) {
        int sa = csr[i], sb = csr[i + 1], sc = csr[i + 2], sd = csr[i + 3];
        half8v va = *(const half8v*)(Hl + (size_t)sa * 64);
        half8v vb = *(const half8v*)(Hl + (size_t)sb * 64);
        half8v vc = *(const half8v*)(Hl + (size_t)sc * 64);
        half8v vd = *(const half8v*)(Hl + (size_t)sd * 64);
        a0 += (float)va[0] + (float)vb[0] + (float)vc[0] + (float)vd[0];
        a1_ += (float)va[1] + (float)vb[1] + (float)vc[1] + (float)vd[1];
        a2 += (float)va[2] + (float)vb[2] + (float)vc[2] + (float)vd[2];
        a3 += (float)va[3] + (float)vb[3] + (float)vc[3] + (float)vd[3];
        a4 += (float)va[4] + (float)vb[4] + (float)vc[4] + (float)vd[4];
        a5 += (float)va[5] + (float)vb[5] + (float)vc[5] + (float)vd[5];
        a6 += (float)va[6] + (float)vb[6] + (float)vc[6] + (float)vd[6];
        a7 += (float)va[7] + (float)vb[7] + (float)vc[7] + (float)vd[7];
    }
    for (; i < e0; ++i) {
        int s = csr[i];
        half8v v = *(const half8v*)(Hl + (size_t)s * 64);
        a0 += (float)v[0]; a1_ += (float)v[1]; a2 += (float)v[2]; a3 += (float)v[3];
        a4 += (float)v[4]; a5 += (float)v[5]; a6 += (float)v[6]; a7 += (float)v[7];
    }
    float4 b0 = *(const float4*)(bias + u * 8);
    float4 b4 = *(const float4*)(bias + u * 8 + 4);
    float* op = Out + (size_t)n * 64 + u * 8;
    *(float4*)op       = make_float4(b0.x + dn * a0, b0.y + dn * a1_, b0.z + dn * a2, b0.w + dn * a3);
    *(float4*)(op + 4) = make_float4(b4.x + dn * a4, b4.y + dn * a5, b4.z + dn * a6, b4.w + dn * a7);
}

extern "C" void kernel_launch(void* const* d_in, const int* in_sizes, int n_in,
                              void* d_out, int out_size, void* d_ws, size_t ws_size,
                              hipStream_t stream) {
    const float* x  = (const float*)d_in[0];
    const int*   ei = (const int*)d_in[1];
    const float* W1 = (const float*)d_in[2];
    const float* b1 = (const float*)d_in[3];
    const float* W2 = (const float*)d_in[4];
    const float* b2 = (const float*)d_in[5];
    float* out = (float*)d_out;
    char* wsb  = (char*)d_ws;

    const int* srcA = ei;
    const int* dstA = ei + NEDGES;

    _Float16* h1h = (_Float16*)wsb;                      // 50000*128 fp16 (16B aligned)
    _Float16* h2h = h1h + (size_t)NNODES * 128;          // 50000*64 fp16
    int*   deg    = (int*)(h2h + (size_t)NNODES * 64);   // 50000
    int*   offs   = deg + NNODES;                        // 50001
    int*   cursor = offs + NNODES + 1;                   // 50000
    float* dinv   = (float*)(cursor + NNODES);           // 50000
    int*   bsum   = (int*)(dinv + NNODES);               // 256
    unsigned short* csr = (unsigned short*)(bsum + 256); // 800000 ushort

    hipMemsetAsync(deg, 0, NNODES * sizeof(int), stream);
    deg_kernel<<<(NEDGES + 255) / 256, 256, 0, stream>>>(dstA, deg, NEDGES);
    scan_local<<<NSCB, 256, 0, stream>>>(deg, offs, bsum, dinv, NNODES);
    scan_addf<<<NSCB, 256, 0, stream>>>(offs, cursor, bsum, NNODES, NSCB);
    fill_kernel<<<(NEDGES + 255) / 256, 256, 0, stream>>>(srcA, dstA, cursor, csr, NEDGES);

    gemm1_mfma<<<(NNODES + 63) / 64, 256, 0, stream>>>(x, W1, dinv, h1h, NNODES);
    agg_gemm_kernel<<<(NNODES + 31) / 32, 512, 0, stream>>>(offs, cursor, csr, dinv, h1h, b1, W2, h2h, NNODES);
    agg2_kernel<<<(NNODES + 31) / 32, 256, 0, stream>>>(offs, cursor, csr, dinv, h2h, b2, out, NNODES);
}

// Round 9
// 158.951 us; speedup vs baseline: 13.3571x; 1.0996x over previous
//
#include <hip/hip_runtime.h>

#define NNODES 50000
#define NEDGES 800000
#define NSCB ((NNODES + 255) / 256)   // 196 scan blocks

typedef _Float16 half2v __attribute__((ext_vector_type(2)));
typedef _Float16 half4v __attribute__((ext_vector_type(4)));
typedef _Float16 half8v __attribute__((ext_vector_type(8)));
typedef float floatx4 __attribute__((ext_vector_type(4)));
typedef unsigned short ushort4v __attribute__((ext_vector_type(4)));

__global__ void deg_kernel(const int* __restrict__ dst, int* __restrict__ deg, int nE) {
    int i = blockIdx.x * blockDim.x + threadIdx.x;
    if (i < nE) atomicAdd(&deg[dst[i]], 1);
}

// local scan (+ fused dinv)
__global__ __launch_bounds__(256) void scan_local(const int* __restrict__ deg,
        int* __restrict__ exc, int* __restrict__ bsum, float* __restrict__ dinv, int n) {
    __shared__ int sm[256];
    int tid = threadIdx.x;
    int i = blockIdx.x * 256 + tid;
    int v = (i < n) ? deg[i] : 0;
    sm[tid] = v;
    __syncthreads();
    for (int off = 1; off < 256; off <<= 1) {
        int t = (tid >= off) ? sm[tid - off] : 0;
        __syncthreads();
        sm[tid] += t;
        __syncthreads();
    }
    if (i < n) {
        exc[i] = sm[tid] - v;
        dinv[i] = 1.0f / sqrtf((float)v + 1.0f);
    }
    if (tid == 255) bsum[blockIdx.x] = sm[255];
}

// each block redundantly scans bsum in LDS, then adds its offset
__global__ __launch_bounds__(256) void scan_addf(int* __restrict__ offs,
        int* __restrict__ cursor, const int* __restrict__ bsum, int n, int nb) {
    __shared__ int sm[256];
    __shared__ int se[256];
    int tid = threadIdx.x;
    int v = (tid < nb) ? bsum[tid] : 0;
    sm[tid] = v;
    __syncthreads();
    for (int off = 1; off < 256; off <<= 1) {
        int t = (tid >= off) ? sm[tid - off] : 0;
        __syncthreads();
        sm[tid] += t;
        __syncthreads();
    }
    se[tid] = sm[tid] - v;
    __syncthreads();
    int boff = se[blockIdx.x];
    int i = blockIdx.x * 256 + tid;
    if (i < n) {
        int o = offs[i] + boff;
        offs[i] = o;
        cursor[i] = o;
    }
}

__global__ void fill_kernel(const int* __restrict__ src, const int* __restrict__ dst,
        int* __restrict__ cursor, unsigned short* __restrict__ csr, int nE) {
    int e = blockIdx.x * blockDim.x + threadIdx.x;
    if (e < nE) {
        int d = dst[e];
        int pos = atomicAdd(&cursor[d], 1);
        csr[pos] = (unsigned short)src[e];
    }
}

// h1w[r,:] = dinv[r] * (X[r,:] @ W1)  via fp16 MFMA, fp16 output.
__global__ __launch_bounds__(256) void gemm1_mfma(
    const float* __restrict__ X, const float* __restrict__ W,
    const float* __restrict__ dinv, _Float16* __restrict__ H, int N)
{
    __shared__ _Float16 outs[64][136];
    const int tid  = threadIdx.x;
    const int lane = tid & 63;
    const int wv   = tid >> 6;
    const int mh   = wv >> 1;
    const int nh   = wv & 1;
    const int t    = lane & 15;
    const int g    = lane >> 4;
    const int row0 = blockIdx.x * 64;

    half8v bf[4][4];
#pragma unroll
    for (int s = 0; s < 4; ++s) {
#pragma unroll
        for (int nt = 0; nt < 4; ++nt) {
            const float* wp = W + (size_t)(s * 32 + g * 8) * 128 + nh * 64 + nt * 16 + t;
            half8v h;
#pragma unroll
            for (int i = 0; i < 8; ++i) h[i] = (_Float16)wp[(size_t)i * 128];
            bf[s][nt] = h;
        }
    }

    floatx4 acc[2][4];
#pragma unroll
    for (int mt = 0; mt < 2; ++mt)
#pragma unroll
        for (int nt = 0; nt < 4; ++nt) acc[mt][nt] = (floatx4){0.f, 0.f, 0.f, 0.f};

#pragma unroll
    for (int s = 0; s < 4; ++s) {
#pragma unroll
        for (int mt = 0; mt < 2; ++mt) {
            int r = row0 + mh * 32 + mt * 16 + t;
            if (r > N - 1) r = N - 1;
            const float* xp = X + (size_t)r * 128 + s * 32 + g * 8;
            float4 x0 = *(const float4*)xp;
            float4 x1 = *(const float4*)(xp + 4);
            half8v af;
            af[0] = (_Float16)x0.x; af[1] = (_Float16)x0.y;
            af[2] = (_Float16)x0.z; af[3] = (_Float16)x0.w;
            af[4] = (_Float16)x1.x; af[5] = (_Float16)x1.y;
            af[6] = (_Float16)x1.z; af[7] = (_Float16)x1.w;
#pragma unroll
            for (int nt = 0; nt < 4; ++nt)
                acc[mt][nt] = __builtin_amdgcn_mfma_f32_16x16x32_f16(af, bf[s][nt], acc[mt][nt], 0, 0, 0);
        }
    }

#pragma unroll
    for (int mt = 0; mt < 2; ++mt) {
#pragma unroll
        for (int r4 = 0; r4 < 4; ++r4) {
            int lrow = mh * 32 + mt * 16 + g * 4 + r4;
            int grow = row0 + lrow;
            if (grow > N - 1) grow = N - 1;
            float dv = dinv[grow];
#pragma unroll
            for (int nt = 0; nt < 4; ++nt)
                outs[lrow][nh * 64 + nt * 16 + t] = (_Float16)(acc[mt][nt][r4] * dv);
        }
    }
    __syncthreads();
    {
        int lrow = tid >> 2, c0 = (tid & 3) * 32;
        int grow = row0 + lrow;
        if (grow < N) {
            const half8v* srcp = (const half8v*)&outs[lrow][c0];
            half8v* dstp = (half8v*)(H + (size_t)grow * 128 + c0);
#pragma unroll
            for (int i = 0; i < 4; ++i) dstp[i] = srcp[i];
        }
    }
}

// fdot2 micro-step: a-pair P (literal), 4 output cols from one W2p half8v
#define FDOT_STEP(P)                                                            \
    {                                                                           \
        half8v wv = *(const half8v*)(wbase + (kq * 4 + P) * 128);               \
        half2v ap = __builtin_shufflevector(av, av, 2 * P, 2 * P + 1);          \
        half2v w0 = __builtin_shufflevector(wv, wv, 0, 1);                      \
        half2v w1 = __builtin_shufflevector(wv, wv, 2, 3);                      \
        half2v w2 = __builtin_shufflevector(wv, wv, 4, 5);                      \
        half2v w3 = __builtin_shufflevector(wv, wv, 6, 7);                      \
        o0 = __builtin_amdgcn_fdot2(ap, w0, o0, false);                         \
        o1 = __builtin_amdgcn_fdot2(ap, w1, o1, false);                         \
        o2 = __builtin_amdgcn_fdot2(ap, w2, o2, false);                         \
        o3 = __builtin_amdgcn_fdot2(ap, w3, o3, false);                         \
    }

// Fused: a1[n] = relu(b1 + dinv[n]*(h1w[n] + sum_s h1w[s]))  (16 lanes/node)
//        h2w[n] = dinv[n] * (a1[n] @ W2)   (fdot2 with k-pair-interleaved W2 in LDS)
__global__ __launch_bounds__(512) void agg_gemm_kernel(
        const int* __restrict__ offs, const int* __restrict__ endo,
        const unsigned short* __restrict__ csr, const float* __restrict__ dinv,
        const _Float16* __restrict__ H1h, const float* __restrict__ b1,
        const float* __restrict__ W2, _Float16* __restrict__ H2h, int nNodes)
{
    __shared__ _Float16 W2p[128 * 64];    // 16 KB, [kp][c][parity]: (k,c) -> (k>>1)*128 + c*2 + (k&1)
    __shared__ _Float16 a1s[32][136];     // 8.5 KB fp16, padded rows
    const int tid = threadIdx.x;

    {   // cooperative W2 load + fp16 convert + pair-interleave store
        const float4* Wg = (const float4*)W2;
#pragma unroll
        for (int i = 0; i < 4; ++i) {
            int idx = tid + i * 512;          // float4 index; k = idx>>4, c0 = (idx&15)*4
            float4 fv = Wg[idx];
            int k = idx >> 4, c0 = (idx & 15) * 4;
            _Float16* base = &W2p[(k >> 1) * 128 + (k & 1)];
            base[(c0 + 0) * 2] = (_Float16)fv.x;
            base[(c0 + 1) * 2] = (_Float16)fv.y;
            base[(c0 + 2) * 2] = (_Float16)fv.z;
            base[(c0 + 3) * 2] = (_Float16)fv.w;
        }
    }
    __syncthreads();

    const int w = tid >> 6, lane = tid & 63;
    const int q = lane >> 4, u = lane & 15;   // 4 nodes/wave, 16 lanes/node
    const int nloc = w * 4 + q;
    const int nid = blockIdx.x * 32 + nloc;

    float a0 = 0.f, a1_ = 0.f, a2 = 0.f, a3 = 0.f, a4 = 0.f, a5 = 0.f, a6 = 0.f, a7 = 0.f;
    float dn = 0.f;
    if (nid < nNodes) {
        dn = dinv[nid];
        const _Float16* Hl = H1h + u * 8;
        half8v sv = *(const half8v*)(Hl + (size_t)nid * 128);
        a0 = (float)sv[0]; a1_ = (float)sv[1]; a2 = (float)sv[2]; a3 = (float)sv[3];
        a4 = (float)sv[4]; a5 = (float)sv[5]; a6 = (float)sv[6]; a7 = (float)sv[7];
        int i = offs[nid], e0 = endo[nid];
        // scalar head until 4-aligned index
        for (; i < e0 && (i & 3); ++i) {
            int s = csr[i];
            half8v v = *(const half8v*)(Hl + (size_t)s * 128);
            a0 += (float)v[0]; a1_ += (float)v[1]; a2 += (float)v[2]; a3 += (float)v[3];
            a4 += (float)v[4]; a5 += (float)v[5]; a6 += (float)v[6]; a7 += (float)v[7];
        }
        // main: 4 edges/iter, vector index load, fp16 pairwise tree (v_pk_add_f16)
        for (; i + 4 <= e0; i += 4) {
            ushort4v ix = *(const ushort4v*)(csr + i);
            half8v va = *(const half8v*)(Hl + (size_t)ix[0] * 128);
            half8v vb = *(const half8v*)(Hl + (size_t)ix[1] * 128);
            half8v vc = *(const half8v*)(Hl + (size_t)ix[2] * 128);
            half8v vd = *(const half8v*)(Hl + (size_t)ix[3] * 128);
            half8v t = (va + vb) + (vc + vd);
            a0 += (float)t[0]; a1_ += (float)t[1]; a2 += (float)t[2]; a3 += (float)t[3];
            a4 += (float)t[4]; a5 += (float)t[5]; a6 += (float)t[6]; a7 += (float)t[7];
        }
        for (; i < e0; ++i) {
            int s = csr[i];
            half8v v = *(const half8v*)(Hl + (size_t)s * 128);
            a0 += (float)v[0]; a1_ += (float)v[1]; a2 += (float)v[2]; a3 += (float)v[3];
            a4 += (float)v[4]; a5 += (float)v[5]; a6 += (float)v[6]; a7 += (float)v[7];
        }
        float4 b0 = *(const float4*)(b1 + u * 8);
        float4 b4 = *(const float4*)(b1 + u * 8 + 4);
        a0 = fmaxf(b0.x + dn * a0, 0.f); a1_ = fmaxf(b0.y + dn * a1_, 0.f);
        a2 = fmaxf(b0.z + dn * a2, 0.f); a3 = fmaxf(b0.w + dn * a3, 0.f);
        a4 = fmaxf(b4.x + dn * a4, 0.f); a5 = fmaxf(b4.y + dn * a5, 0.f);
        a6 = fmaxf(b4.z + dn * a6, 0.f); a7 = fmaxf(b4.w + dn * a7, 0.f);
    }
    {
        half8v ah;
        ah[0] = (_Float16)a0; ah[1] = (_Float16)a1_; ah[2] = (_Float16)a2; ah[3] = (_Float16)a3;
        ah[4] = (_Float16)a4; ah[5] = (_Float16)a5; ah[6] = (_Float16)a6; ah[7] = (_Float16)a7;
        *(half8v*)&a1s[nloc][u * 8] = ah;
    }
    // phase 2 reads only own-wave rows; wave-local RAW -> waitcnt suffices
    asm volatile("s_waitcnt lgkmcnt(0)" ::: "memory");

    // phase 2: node nloc, cols u*4..u*4+3 via fdot2 (k-pairs)
    {
        float o0 = 0.f, o1 = 0.f, o2 = 0.f, o3 = 0.f;
        const _Float16* arow = &a1s[nloc][0];
        const _Float16* wbase = &W2p[u * 8];
#pragma unroll 4
        for (int kq = 0; kq < 16; ++kq) {                 // 8 k's = 4 pairs per iter
            half8v av = *(const half8v*)(arow + kq * 8);
            FDOT_STEP(0)
            FDOT_STEP(1)
            FDOT_STEP(2)
            FDOT_STEP(3)
        }
        if (nid < nNodes) {
            half4v o;
            o[0] = (_Float16)(dn * o0); o[1] = (_Float16)(dn * o1);
            o[2] = (_Float16)(dn * o2); o[3] = (_Float16)(dn * o3);
            *(half4v*)(H2h + (size_t)nid * 64 + u * 4) = o;
        }
    }
}

// out[n] = b2 + dinv[n]*( h2w[n] + sum_s h2w[s] ), 8 lanes/node, fp16 tree
__global__ __launch_bounds__(256) void agg2_kernel(
        const int* __restrict__ offs, const int* __restrict__ endo,
        const unsigned short* __restrict__ csr, const float* __restrict__ dinv,
        const _Float16* __restrict__ Hh, const float* __restrict__ bias,
        float* __restrict__ Out, int nNodes)
{
    const int tid = threadIdx.x;
    const int w = tid >> 6, lane = tid & 63;
    const int q = lane >> 3, u = lane & 7;    // 8 nodes/wave, 8 lanes/node
    const int n = blockIdx.x * 32 + w * 8 + q;
    if (n >= nNodes) return;
    float dn = dinv[n];
    const _Float16* Hl = Hh + u * 8;
    half8v sv = *(const half8v*)(Hl + (size_t)n * 64);
    float a0 = (float)sv[0], a1_ = (float)sv[1], a2 = (float)sv[2], a3 = (float)sv[3];
    float a4 = (float)sv[4], a5 = (float)sv[5], a6 = (float)sv[6], a7 = (float)sv[7];
    int i = offs[n], e0 = endo[n];
    for (; i < e0 && (i & 3); ++i) {
        int s = csr[i];
        half8v v = *(const half8v*)(Hl + (size_t)s * 64);
        a0 += (float)v[0]; a1_ += (float)v[1]; a2 += (float)v[2]; a3 += (float)v[3];
        a4 += (float)v[4]; a5 += (float)v[5]; a6 += (float)v[6]; a7 += (float)v[7];
    }
    for (; i + 4 <= e0; i += 4) {
        ushort4v ix = *(const ushort4v*)(csr + i);
        half8v va = *(const half8v*)(Hl + (size_t)ix[0] * 64);
        half8v vb = *(const half8v*)(Hl + (size_t)ix[1] * 64);
        half8v vc = *(const half8v*)(Hl + (size_t)ix[2] * 64);
        half8v vd = *(const half8v*)(Hl + (size_t)ix[3] * 64);
        half8v t = (va + vb) + (vc + vd);
        a0 += (float)t[0]; a1_ += (float)t[1]; a2 += (float)t[2]; a3 += (float)t[3];
        a4 += (float)t[4]; a5 += (float)t[5]; a6 += (float)t[6]; a7 += (float)t[7];
    }
    for (; i < e0; ++i) {
        int s = csr[i];
        half8v v = *(const half8v*)(Hl + (size_t)s * 64);
        a0 += (float)v[0]; a1_ += (float)v[1]; a2 += (float)v[2]; a3 += (float)v[3];
        a4 += (float)v[4]; a5 += (float)v[5]; a6 += (float)v[6]; a7 += (float)v[7];
    }
    float4 b0 = *(const float4*)(bias + u * 8);
    float4 b4 = *(const float4*)(bias + u * 8 + 4);
    float* op = Out + (size_t)n * 64 + u * 8;
    *(float4*)op       = make_float4(b0.x + dn * a0, b0.y + dn * a1_, b0.z + dn * a2, b0.w + dn * a3);
    *(float4*)(op + 4) = make_float4(b4.x + dn * a4, b4.y + dn * a5, b4.z + dn * a6, b4.w + dn * a7);
}

extern "C" void kernel_launch(void* const* d_in, const int* in_sizes, int n_in,
                              void* d_out, int out_size, void* d_ws, size_t ws_size,
                              hipStream_t stream) {
    const float* x  = (const float*)d_in[0];
    const int*   ei = (const int*)d_in[1];
    const float* W1 = (const float*)d_in[2];
    const float* b1 = (const float*)d_in[3];
    const float* W2 = (const float*)d_in[4];
    const float* b2 = (const float*)d_in[5];
    float* out = (float*)d_out;
    char* wsb  = (char*)d_ws;

    const int* srcA = ei;
    const int* dstA = ei + NEDGES;

    _Float16* h1h = (_Float16*)wsb;                      // 50000*128 fp16 (base: 16B aligned)
    _Float16* h2h = h1h + (size_t)NNODES * 128;          // 50000*64 fp16
    unsigned short* csr = (unsigned short*)(h2h + (size_t)NNODES * 64); // 800000 ushort, 16B aligned
    int*   deg    = (int*)(csr + NEDGES);                // 50000
    int*   offs   = deg + NNODES;                        // 50001
    int*   cursor = offs + NNODES + 1;                   // 50000
    float* dinv   = (float*)(cursor + NNODES);           // 50000
    int*   bsum   = (int*)(dinv + NNODES);               // 256

    (void)hipMemsetAsync(deg, 0, NNODES * sizeof(int), stream);
    deg_kernel<<<(NEDGES + 255) / 256, 256, 0, stream>>>(dstA, deg, NEDGES);
    scan_local<<<NSCB, 256, 0, stream>>>(deg, offs, bsum, dinv, NNODES);
    scan_addf<<<NSCB, 256, 0, stream>>>(offs, cursor, bsum, NNODES, NSCB);
    fill_kernel<<<(NEDGES + 255) / 256, 256, 0, stream>>>(srcA, dstA, cursor, csr, NEDGES);

    gemm1_mfma<<<(NNODES + 63) / 64, 256, 0, stream>>>(x, W1, dinv, h1h, NNODES);
    agg_gemm_kernel<<<(NNODES + 31) / 32, 512, 0, stream>>>(offs, cursor, csr, dinv, h1h, b1, W2, h2h, NNODES);
    agg2_kernel<<<(NNODES + 31) / 32, 256, 0, stream>>>(offs, cursor, csr, dinv, h2h, b2, out, NNODES);
}